// Round 8
// baseline (613.264 us; speedup 1.0000x reference)
//
#include <hip/hip_runtime.h>
#include <hip/hip_bf16.h>
#include <math.h>

// Problem constants
#define N_NODES 50000
#define E_EDGES 500000
#define G_GRAPHS 128
#define N_PAD 50176   // 196*256 = 49*1024, padded node count for scan
// H = 256, NF = 64, EDGE_IN = 905 (rows: hi 0..255 | hj 256..511 | lat 512..520 | fd 521..904)

typedef _Float16 f16;
typedef _Float16 half8 __attribute__((ext_vector_type(8)));
typedef _Float16 half4 __attribute__((ext_vector_type(4)));
typedef float f32x4 __attribute__((ext_vector_type(4)));

// silu via v_rcp: avoids the precise-divide expansion (~9 instrs) of 1.0f/x
__device__ __forceinline__ float fast_silu(float x) {
    return x * __builtin_amdgcn_rcpf(1.0f + __expf(-x));
}

// ---------------------------------------------------------------------------
// Pack helper (device): [K x 256] row-major fp32 -> MFMA fragment-linear f16.
// chunk (nb, kstep): lane holds W[k=kstep*32+(lane>>4)*8+j][n=nb*16+(lane&15)].
// Serves BOTH as B-fragment (k,n) and as A-fragment (n,k) of W^T for the
// operand-swapped GEMMs.
// ---------------------------------------------------------------------------
__device__ __forceinline__ void pack_dev(const float* __restrict__ src,
                                         f16* __restrict__ dst, int Ksteps, int ltid) {
    int lane = ltid & 63;
    int chunk = ltid >> 6;
    int kstep = chunk % Ksteps;
    int nb = chunk / Ksteps;
    if (nb >= 16) return;
    int n = nb * 16 + (lane & 15);
    int k0 = kstep * 32 + (lane >> 4) * 8;
    f16* d = dst + (size_t)ltid * 8;
#pragma unroll
    for (int j = 0; j < 8; ++j)
        d[j] = (f16)src[(size_t)(k0 + j) * 256 + n];
}

// ---------------------------------------------------------------------------
// Fused prep: 7 weight packs + latW + edge histogram in ONE launch.
// ---------------------------------------------------------------------------
__global__ __launch_bounds__(256) void prep_fused(
    const float* __restrict__ eW1, const float* __restrict__ eW2,
    const float* __restrict__ nW1, const float* __restrict__ nW2,
    f16* __restrict__ Wfd, f16* __restrict__ Whi, f16* __restrict__ Whj,
    f16* __restrict__ We2, f16* __restrict__ Wn1h, f16* __restrict__ Wn1a,
    f16* __restrict__ Wn2,
    const float* __restrict__ lat, const float* __restrict__ eb1,
    f16* __restrict__ latW16,
    const int* __restrict__ ei, int* __restrict__ cnt)
{
    int b = blockIdx.x, t = threadIdx.x;
    if (b < 48)        { pack_dev(eW1 + 521 * 256, Wfd,  12, b * 256 + t); }
    else if (b < 80)   { pack_dev(eW1,             Whi,  8, (b - 48) * 256 + t); }
    else if (b < 112)  { pack_dev(eW1 + 256 * 256, Whj,  8, (b - 80) * 256 + t); }
    else if (b < 144)  { pack_dev(eW2,             We2,  8, (b - 112) * 256 + t); }
    else if (b < 176)  { pack_dev(nW1,             Wn1h, 8, (b - 144) * 256 + t); }
    else if (b < 208)  { pack_dev(nW1 + 256 * 256, Wn1a, 8, (b - 176) * 256 + t); }
    else if (b < 240)  { pack_dev(nW2,             Wn2,  8, (b - 208) * 256 + t); }
    else if (b < 368) {
        int g = b - 240, n = t;
        float l[9];
#pragma unroll
        for (int i = 0; i < 9; ++i) l[i] = lat[g * 9 + i];
        float acc = eb1[n];
#pragma unroll
        for (int i = 0; i < 3; ++i)
#pragma unroll
            for (int j = 0; j < 3; ++j) {
                float ip = l[i*3+0]*l[j*3+0] + l[i*3+1]*l[j*3+1] + l[i*3+2]*l[j*3+2];
                acc += ip * eW1[(size_t)(512 + i*3 + j) * 256 + n];
            }
        latW16[g * 256 + n] = (f16)acc;
    } else {
        int e = (b - 368) * 256 + t;
        if (e < E_EDGES) atomicAdd(cnt + ei[e], 1);
    }
}

// ---------------------------------------------------------------------------
// Parallel CSR scan: per-block exclusive scan + block totals, then a single
// wave scans the 49 totals. pos adds base[s>>10].
// ---------------------------------------------------------------------------
__global__ __launch_bounds__(1024) void scan_part(const int* __restrict__ cnt,
                                                  int* __restrict__ off,
                                                  int* __restrict__ partials) {
    __shared__ int wsum[16], wpre[16];
    int t = threadIdx.x, lane = t & 63, w = t >> 6;
    int c = blockIdx.x * 1024 + t;
    int v = cnt[c];
    int x = v;
#pragma unroll
    for (int d = 1; d < 64; d <<= 1) { int nn = __shfl_up(x, d); if (lane >= d) x += nn; }
    if (lane == 63) wsum[w] = x;
    __syncthreads();
    if (t < 16) {
        int s = wsum[t];
        int y = s;
#pragma unroll
        for (int d = 1; d < 16; d <<= 1) { int nn = __shfl_up(y, d, 16); if (t >= d) y += nn; }
        wpre[t] = y - s;
        if (t == 15) partials[blockIdx.x] = y;
    }
    __syncthreads();
    off[c] = wpre[w] + x - v;   // block-local exclusive
}

__global__ void scan_tops(const int* __restrict__ partials, int* __restrict__ base) {
    int t = threadIdx.x;   // 64 threads, 49 used
    int v = (t < 49) ? partials[t] : 0;
    int x = v;
#pragma unroll
    for (int d = 1; d < 64; d <<= 1) { int nn = __shfl_up(x, d); if (t >= d) x += nn; }
    if (t < 49) base[t] = x - v;   // exclusive
}

__global__ void pos_kernel(const int* __restrict__ ei, const int* __restrict__ off,
                           const int* __restrict__ base, int* __restrict__ tmp,
                           int* __restrict__ sorted_e) {
    int e = blockIdx.x * 256 + threadIdx.x;
    if (e >= E_EDGES) return;
    int s = ei[e];
    int p = off[s] + base[s >> 10] + atomicAdd(tmp + s, 1);
    sorted_e[p] = e;
}

// ---------------------------------------------------------------------------
// LayerNorm(h) then three OPERAND-SWAPPED GEMMs -> f16 outputs Hh1/Hh2/Nh.
// Load phase: 16-lanes-per-row mapping -> contiguous 256 B per-row loads;
// row stats via 4-level shfl_xor within the 16-lane group.
// ---------------------------------------------------------------------------
__global__ __launch_bounds__(256) void ln_gemm_kernel(
    const float* __restrict__ h, const float* __restrict__ gamma, const float* __restrict__ beta,
    const f16* __restrict__ Whi, const f16* __restrict__ Whj, const f16* __restrict__ Wn1,
    f16* __restrict__ Hh1, f16* __restrict__ Hh2, f16* __restrict__ Nh)
{
    __shared__ f16 Aln[64 * 264];
    int tid = threadIdx.x;
    int l15g = tid & 15;          // col-group lane
    int rq   = tid >> 4;          // 0..15: row slot within a round

    // hoist gamma/beta for this lane's cols: (l15g + 16*i) float4, i=0..3
    float4 gv[4], bv[4];
#pragma unroll
    for (int i = 0; i < 4; ++i) {
        gv[i] = ((const float4*)gamma)[l15g + 16*i];
        bv[i] = ((const float4*)beta )[l15g + 16*i];
    }

#pragma unroll
    for (int r4 = 0; r4 < 4; ++r4) {
        int rl = r4 * 16 + rq;                 // local row 0..63
        int row = blockIdx.x * 64 + rl;
        int rowc = min(row, N_NODES - 1);
        const float4* hp4 = (const float4*)(h + (size_t)rowc * 256);
        float4 xv[4];
        float s = 0.f, ss = 0.f;
#pragma unroll
        for (int i = 0; i < 4; ++i) {
            float4 x = hp4[l15g + 16*i];
            xv[i] = x;
            s  += x.x + x.y + x.z + x.w;
            ss += x.x*x.x + x.y*x.y + x.z*x.z + x.w*x.w;
        }
#pragma unroll
        for (int m = 1; m < 16; m <<= 1) {
            s  += __shfl_xor(s,  m);
            ss += __shfl_xor(ss, m);
        }
        float mean = s * (1.f / 256.f);
        float var  = ss * (1.f / 256.f) - mean * mean;
        float rstd = rsqrtf(var + 1e-5f);
#pragma unroll
        for (int i = 0; i < 4; ++i) {
            half4 o;
            o[0] = (f16)((xv[i].x - mean) * rstd * gv[i].x + bv[i].x);
            o[1] = (f16)((xv[i].y - mean) * rstd * gv[i].y + bv[i].y);
            o[2] = (f16)((xv[i].z - mean) * rstd * gv[i].z + bv[i].z);
            o[3] = (f16)((xv[i].w - mean) * rstd * gv[i].w + bv[i].w);
            *(half4*)(Aln + rl * 264 + (l15g + 16*i) * 4) = o;
        }
    }
    __syncthreads();

    int lane = tid & 63, w = tid >> 6;
    int l15 = lane & 15, q = lane >> 4;
    const f16* Ws[3] = {Whi, Whj, Wn1};
    f16* Os[3] = {Hh1, Hh2, Nh};
    const f32x4 z4 = {0.f, 0.f, 0.f, 0.f};

    for (int widx = 0; widx < 3; ++widx) {
        f32x4 acc[4][4];   // [mi Hcol-block][g node-group]
#pragma unroll
        for (int a = 0; a < 4; ++a)
#pragma unroll
            for (int b = 0; b < 4; ++b) acc[a][b] = z4;
        const f16* W = Ws[widx];
        for (int ks = 0; ks < 8; ++ks) {
            half8 bfr[4];
#pragma unroll
            for (int g = 0; g < 4; ++g)
                bfr[g] = *(const half8*)(Aln + (g*16 + l15) * 264 + ks*32 + q*8);
#pragma unroll
            for (int mi = 0; mi < 4; ++mi) {
                half8 afr = *(const half8*)(W + ((size_t)((w*4 + mi)*8 + ks) * 64 + lane) * 8);
#pragma unroll
                for (int g = 0; g < 4; ++g)
                    acc[mi][g] = __builtin_amdgcn_mfma_f32_16x16x32_f16(afr, bfr[g], acc[mi][g], 0, 0, 0);
            }
        }
        f16* O = Os[widx];
#pragma unroll
        for (int g = 0; g < 4; ++g) {
            int orow = blockIdx.x * 64 + g*16 + l15;
            if (orow < N_NODES) {
#pragma unroll
                for (int mi = 0; mi < 4; ++mi) {
                    int hc0 = (w*4 + mi) * 16 + q * 4;
                    half4 hv;
                    hv[0] = (f16)acc[mi][g][0]; hv[1] = (f16)acc[mi][g][1];
                    hv[2] = (f16)acc[mi][g][2]; hv[3] = (f16)acc[mi][g][3];
                    *(half4*)(O + (size_t)orow * 256 + hc0) = hv;
                }
            }
        }
    }
}

// ---------------------------------------------------------------------------
// Edge kernel v13: v12 + bijective XCD-chunked block swizzle.
// R7 showed 5-block occupancy inflated HBM traffic (FETCH 242->293 MB, WRITE
// 64->173 MB): consecutive blocks share src-node locality (sorted edges) and
// write adjacent aggsum rows, but round-robin dispatch scatters them across
// 8 private L2s -> each XCD re-fetches the same Hh1/Hh2 rows and aggsum
// atomic lines thrash (written back ~3x). Chunked swizzle (m204 bijective
// formula, works for nwg%8!=0) gives each XCD a contiguous ~1953-block run:
// its aggsum/Hh1 footprint becomes a contiguous ~6 MB range.
// ---------------------------------------------------------------------------
__global__ __launch_bounds__(256, 5) void edge_kernel(
    const int* __restrict__ sorted_e,
    const int* __restrict__ edge_index, const int* __restrict__ edge2graph,
    const float* __restrict__ frac_diff,
    const f16* __restrict__ Hh1, const f16* __restrict__ Hh2, const f16* __restrict__ latW16,
    const f16* __restrict__ Wfd, const f16* __restrict__ We2, const float* __restrict__ eb2,
    float* __restrict__ aggsum)
{
    __shared__ f16 bufA[32 * 264];   // 16.9 KB: R tile -> e1 tile -> e2 tile
    __shared__ f16 bufB[6144];       // 12.3 KB: sinusoid frag pass window
    __shared__ float frac_s[32][4];
    __shared__ int src_s[32], dst_s[32], g_s[32], srcr[32];
    int tid = threadIdx.x;

    // XCD-chunked bijective swizzle: orig%8 = XCD slot, orig/8 = position.
    int nwg = gridDim.x;
    int orig = blockIdx.x;
    int xcd = orig & 7, pos = orig >> 3;
    int qc = nwg >> 3, rc = nwg & 7;
    int bid = (xcd < rc ? xcd * (qc + 1) : rc * (qc + 1) + (xcd - rc) * qc) + pos;
    int e0 = bid * 32;

    if (tid < 32) {
        int slot = e0 + tid;
        int e = (slot < E_EDGES) ? sorted_e[slot] : -1;
        int ec = e < 0 ? 0 : e;
        int sv = edge_index[ec];
        src_s[tid] = sv;
        dst_s[tid] = edge_index[E_EDGES + ec];
        g_s[tid]   = edge2graph[ec];
        srcr[tid]  = (e < 0) ? -1 : sv;
        frac_s[tid][0] = frac_diff[(size_t)ec * 3 + 0];
        frac_s[tid][1] = frac_diff[(size_t)ec * 3 + 1];
        frac_s[tid][2] = frac_diff[(size_t)ec * 3 + 2];
    }
    __syncthreads();   // B1: indices + frac ready

    // Stage one pass: 384 units (row 32, z 3, q2 4), <=2 per thread.
    auto stage_pass = [&](int p) {
#pragma unroll
        for (int uu = 0; uu < 2; ++uu) {
            int u = tid + uu * 256;
            if (u < 384) {
                int row = u & 31;
                int zz = u >> 5;           // 0..11 = z*4 + q2
                int z = zz >> 2, q2 = zz & 3;
                int kg = p * 3 + z;
                int d = kg >> 1, fb = kg & 1;
                float x = frac_s[row][d];
                float c1 = __builtin_amdgcn_cosf(x);
                float s1 = __builtin_amdgcn_sinf(x);
                float t0 = x * (float)(fb * 32 + q2 * 8);
                float rev = t0 - floorf(t0);
                float s = __builtin_amdgcn_sinf(rev);
                float c = __builtin_amdgcn_cosf(rev);
                f16 avs[8], avc[8];
#pragma unroll
                for (int j = 0; j < 8; ++j) {
                    avs[j] = (f16)s; avc[j] = (f16)c;
                    float ns = s * c1 + c * s1;
                    float nc = c * c1 - s * s1;
                    s = ns; c = nc;
                }
                int mb = row >> 4;
                int lslot = (row & 15) + 16 * q2;
                *(half8*)(bufB + (((z    ) * 2 + mb) * 64 + lslot) * 8) = *(half8*)avs;
                *(half8*)(bufB + (((z + 3) * 2 + mb) * 64 + lslot) * 8) = *(half8*)avc;
            }
        }
    };

    // ---- R-fill: thread owns row m = tid>>3; chunks cc = (tid&7) + 8*i.
    {
        int m = tid >> 3, c0 = tid & 7;
        const f16* pa = Hh1    + (size_t)src_s[m] * 256 + c0 * 8;
        const f16* pb = Hh2    + (size_t)dst_s[m] * 256 + c0 * 8;
        const f16* pc = latW16 + (size_t)g_s[m]   * 256 + c0 * 8;
        f16* pd = bufA + m * 264 + c0 * 8;
#pragma unroll
        for (int i = 0; i < 4; ++i) {
            half8 a = *(const half8*)(pa + i * 64);
            half8 b = *(const half8*)(pb + i * 64);
            half8 c = *(const half8*)(pc + i * 64);
            *(half8*)(pd + i * 64) = a + b + c;
        }
    }
    stage_pass(0);
    __syncthreads();   // B2: R tile + pass-0 frags ready

    int lane = tid & 63, w = tid >> 6;
    int l15 = lane & 15, q = lane >> 4;

    // ---- swapped GEMM1: e1^T[Hcol][edge] = Wfd^T @ fd^T + R^T.
    f32x4 acc[4][2];
#pragma unroll
    for (int mi = 0; mi < 4; ++mi)
#pragma unroll
        for (int g = 0; g < 2; ++g) {
            int edge = g * 16 + l15;
            int hc0 = (w*4 + mi) * 16 + q * 4;
            half4 rv = *(const half4*)(bufA + edge * 264 + hc0);
            f32x4 a;
            a[0] = (float)rv[0]; a[1] = (float)rv[1];
            a[2] = (float)rv[2]; a[3] = (float)rv[3];
            acc[mi][g] = a;
        }

#pragma unroll
    for (int p = 0; p < 2; ++p) {
        if (p == 1) {
            __syncthreads();   // B2b: pass-0 frag reads done
            stage_pass(1);
            __syncthreads();   // B2c: pass-1 frags ready
        }
#pragma unroll
        for (int z = 0; z < 3; ++z) {
            int kg = p * 3 + z;
            half8 aS[4], aC[4];
#pragma unroll
            for (int mi = 0; mi < 4; ++mi) {
                int mblk = w * 4 + mi;
                aS[mi] = *(const half8*)(Wfd + ((size_t)(mblk*12 + kg)     * 64 + lane) * 8);
                aC[mi] = *(const half8*)(Wfd + ((size_t)(mblk*12 + kg + 6) * 64 + lane) * 8);
            }
#pragma unroll
            for (int g = 0; g < 2; ++g) {
                half8 bS = *(const half8*)(bufB + (((z    ) * 2 + g) * 64 + lane) * 8);
                half8 bC = *(const half8*)(bufB + (((z + 3) * 2 + g) * 64 + lane) * 8);
#pragma unroll
                for (int mi = 0; mi < 4; ++mi) {
                    acc[mi][g] = __builtin_amdgcn_mfma_f32_16x16x32_f16(aS[mi], bS, acc[mi][g], 0, 0, 0);
                    acc[mi][g] = __builtin_amdgcn_mfma_f32_16x16x32_f16(aC[mi], bC, acc[mi][g], 0, 0, 0);
                }
            }
        }
    }

    // ---- epilogue 1: silu -> e1 row-major [edge][264] (owner-exclusive)
#pragma unroll
    for (int mi = 0; mi < 4; ++mi)
#pragma unroll
        for (int g = 0; g < 2; ++g) {
            int edge = g * 16 + l15;
            int hc0 = (w*4 + mi) * 16 + q * 4;
            half4 tv;
            tv[0] = (f16)fast_silu(acc[mi][g][0]);
            tv[1] = (f16)fast_silu(acc[mi][g][1]);
            tv[2] = (f16)fast_silu(acc[mi][g][2]);
            tv[3] = (f16)fast_silu(acc[mi][g][3]);
            *(half4*)(bufA + edge * 264 + hc0) = tv;
        }
    __syncthreads();   // B3: e1 tile ready (also: all pass-1 frag reads done)

    // ---- swapped GEMM2: e2^T = We2^T @ e1^T
    f32x4 acc2[4][2];
    const f32x4 z4 = {0.f, 0.f, 0.f, 0.f};
#pragma unroll
    for (int a = 0; a < 4; ++a)
#pragma unroll
        for (int b = 0; b < 2; ++b) acc2[a][b] = z4;
#pragma unroll
    for (int ks = 0; ks < 8; ++ks) {
        half8 bfr[2];
#pragma unroll
        for (int g = 0; g < 2; ++g)
            bfr[g] = *(const half8*)(bufA + (g*16 + l15) * 264 + ks*32 + q*8);
#pragma unroll
        for (int mi = 0; mi < 4; ++mi) {
            half8 afr = *(const half8*)(We2 + ((size_t)((w*4 + mi)*8 + ks) * 64 + lane) * 8);
#pragma unroll
            for (int g = 0; g < 2; ++g)
                acc2[mi][g] = __builtin_amdgcn_mfma_f32_16x16x32_f16(afr, bfr[g], acc2[mi][g], 0, 0, 0);
        }
    }
    __syncthreads();   // B3b: all e1 B-frag reads done (WAR cover for e2 write)

    // ---- epilogue 2: silu(+eb2) -> e2 tile in bufA [edge][264] (half4 stores)
    {
        float msk[2];
#pragma unroll
        for (int g = 0; g < 2; ++g)
            msk[g] = (srcr[g*16 + l15] >= 0) ? 1.f : 0.f;
#pragma unroll
        for (int mi = 0; mi < 4; ++mi) {
            int hc0 = (w*4 + mi) * 16 + q * 4;
            float4 e4 = *(const float4*)(eb2 + hc0);
#pragma unroll
            for (int g = 0; g < 2; ++g) {
                int edge = g * 16 + l15;
                half4 tv;
                tv[0] = (f16)(fast_silu(acc2[mi][g][0] + e4.x) * msk[g]);
                tv[1] = (f16)(fast_silu(acc2[mi][g][1] + e4.y) * msk[g]);
                tv[2] = (f16)(fast_silu(acc2[mi][g][2] + e4.z) * msk[g]);
                tv[3] = (f16)(fast_silu(acc2[mi][g][3] + e4.w) * msk[g]);
                *(half4*)(bufA + edge * 264 + hc0) = tv;
            }
        }
    }
    __syncthreads();   // B4: e2 tile ready

    // ---- segmented reduction: thread t owns Hcol t; rows scanned serially.
    // Per row, 64 lanes read 64 consecutive halfs (32 dwords) -> conflict-free.
    {
        int t = tid;
        float run = 0.f;
        int cur = srcr[0];
#pragma unroll
        for (int mm = 0; mm < 32; ++mm) {
            int s = srcr[mm];
            float v = (float)bufA[mm * 264 + t];
            if (s != cur) {
                if (cur >= 0) atomicAdd(aggsum + (size_t)cur * 256 + t, run);
                cur = s; run = v;
            } else run += v;
        }
        if (cur >= 0) atomicAdd(aggsum + (size_t)cur * 256 + t, run);
    }
}

// ---------------------------------------------------------------------------
// Node post (operand-swapped): agg = aggsum/max(cnt,1);
// t = silu(Nh + agg@Wn1a + nb1); out = h + silu(t@Wn2 + nb2).
// Load phase: linear lane-major mapping -> 1 KB contiguous per instruction.
// ---------------------------------------------------------------------------
__global__ __launch_bounds__(256) void node_post_kernel(
    const float* __restrict__ aggsum, const int* __restrict__ cnt,
    const f16* __restrict__ Nh, const f16* __restrict__ Wn1a, const f16* __restrict__ Wn2,
    const float* __restrict__ nb1, const float* __restrict__ nb2,
    const float* __restrict__ h, float* __restrict__ out)
{
    __shared__ f16 T[64 * 264];
    int tid = threadIdx.x;
    int lane = tid & 63, w = tid >> 6;
    {
#pragma unroll
        for (int i = 0; i < 16; ++i) {
            int rl = w + 4 * i;                 // local row 0..63, wave-uniform
            int row = blockIdx.x * 64 + rl;
            int rowc = min(row, N_NODES - 1);
            float inv = 1.f / fmaxf((float)cnt[rowc], 1.f);
            float4 x = ((const float4*)(aggsum + (size_t)rowc * 256))[lane];
            half4 av;
            av[0] = (f16)(x.x * inv);
            av[1] = (f16)(x.y * inv);
            av[2] = (f16)(x.z * inv);
            av[3] = (f16)(x.w * inv);
            *(half4*)(T + rl * 264 + lane * 4) = av;
        }
    }
    __syncthreads();

    int l15 = lane & 15, q = lane >> 4;
    const f32x4 z4 = {0.f, 0.f, 0.f, 0.f};

    // GEMM1 swapped: acc[mi][g], A = Wn1a frag, B = T rows (agg)
    f32x4 acc[4][4];
#pragma unroll
    for (int a = 0; a < 4; ++a)
#pragma unroll
        for (int b = 0; b < 4; ++b) acc[a][b] = z4;
    for (int ks = 0; ks < 8; ++ks) {
        half8 bfr[4];
#pragma unroll
        for (int g = 0; g < 4; ++g)
            bfr[g] = *(const half8*)(T + (g*16 + l15) * 264 + ks*32 + q*8);
#pragma unroll
        for (int mi = 0; mi < 4; ++mi) {
            half8 afr = *(const half8*)(Wn1a + ((size_t)((w*4 + mi)*8 + ks) * 64 + lane) * 8);
#pragma unroll
            for (int g = 0; g < 4; ++g)
                acc[mi][g] = __builtin_amdgcn_mfma_f32_16x16x32_f16(afr, bfr[g], acc[mi][g], 0, 0, 0);
        }
    }
    __syncthreads();   // all T reads done

    // t = silu(acc + Nh + nb1) -> T'[node][hc0..3] half4 writes
#pragma unroll
    for (int mi = 0; mi < 4; ++mi) {
        int hc0 = (w*4 + mi) * 16 + q * 4;
        f32x4 b1v = *(const f32x4*)(nb1 + hc0);
#pragma unroll
        for (int g = 0; g < 4; ++g) {
            int nodeg = blockIdx.x * 64 + g*16 + l15;
            int orc = min(nodeg, N_NODES - 1);
            half4 nh4 = *(const half4*)(Nh + (size_t)orc * 256 + hc0);
            half4 tv;
            tv[0] = (f16)fast_silu(acc[mi][g][0] + (float)nh4[0] + b1v[0]);
            tv[1] = (f16)fast_silu(acc[mi][g][1] + (float)nh4[1] + b1v[1]);
            tv[2] = (f16)fast_silu(acc[mi][g][2] + (float)nh4[2] + b1v[2]);
            tv[3] = (f16)fast_silu(acc[mi][g][3] + (float)nh4[3] + b1v[3]);
            *(half4*)(T + (g*16 + l15) * 264 + hc0) = tv;
        }
    }
    __syncthreads();

    // GEMM2 swapped: A = Wn2 frag, B = T' rows
    f32x4 acc2[4][4];
#pragma unroll
    for (int a = 0; a < 4; ++a)
#pragma unroll
        for (int b = 0; b < 4; ++b) acc2[a][b] = z4;
    for (int ks = 0; ks < 8; ++ks) {
        half8 bfr[4];
#pragma unroll
        for (int g = 0; g < 4; ++g)
            bfr[g] = *(const half8*)(T + (g*16 + l15) * 264 + ks*32 + q*8);
#pragma unroll
        for (int mi = 0; mi < 4; ++mi) {
            half8 afr = *(const half8*)(Wn2 + ((size_t)((w*4 + mi)*8 + ks) * 64 + lane) * 8);
#pragma unroll
            for (int g = 0; g < 4; ++g)
                acc2[mi][g] = __builtin_amdgcn_mfma_f32_16x16x32_f16(afr, bfr[g], acc2[mi][g], 0, 0, 0);
        }
    }

    // out = h + silu(acc2 + nb2) -> float4 stores
#pragma unroll
    for (int g = 0; g < 4; ++g) {
        int orow = blockIdx.x * 64 + g*16 + l15;
        if (orow < N_NODES) {
#pragma unroll
            for (int mi = 0; mi < 4; ++mi) {
                int hc0 = (w*4 + mi) * 16 + q * 4;
                f32x4 b2v = *(const f32x4*)(nb2 + hc0);
                f32x4 hv  = *(const f32x4*)(h + (size_t)orow * 256 + hc0);
                f32x4 ov;
                ov[0] = hv[0] + fast_silu(acc2[mi][g][0] + b2v[0]);
                ov[1] = hv[1] + fast_silu(acc2[mi][g][1] + b2v[1]);
                ov[2] = hv[2] + fast_silu(acc2[mi][g][2] + b2v[2]);
                ov[3] = hv[3] + fast_silu(acc2[mi][g][3] + b2v[3]);
                *(f32x4*)(out + (size_t)orow * 256 + hc0) = ov;
            }
        }
    }
}

// ---------------------------------------------------------------------------
extern "C" void kernel_launch(void* const* d_in, const int* in_sizes, int n_in,
                              void* d_out, int out_size, void* d_ws, size_t ws_size,
                              hipStream_t stream) {
    const float* h          = (const float*)d_in[0];
    const float* lattices   = (const float*)d_in[2];
    const int*   edge_index = (const int*)d_in[3];
    const int*   edge2graph = (const int*)d_in[4];
    const float* frac_diff  = (const float*)d_in[5];
    const float* ln_gamma   = (const float*)d_in[6];
    const float* ln_beta    = (const float*)d_in[7];
    const float* eW1        = (const float*)d_in[8];
    const float* eb1        = (const float*)d_in[9];
    const float* eW2        = (const float*)d_in[10];
    const float* eb2        = (const float*)d_in[11];
    const float* nW1        = (const float*)d_in[12];
    const float* nb1        = (const float*)d_in[13];
    const float* nW2        = (const float*)d_in[14];
    const float* nb2        = (const float*)d_in[15];
    float* out = (float*)d_out;
    char* base = (char*)d_ws;

    // workspace layout (byte offsets)
    float* aggsum   = (float*)(base + 0);              // 51,200,000 B
    int*   cnt      = (int*)  (base + 51200000);       // 200,704
    int*   off      = (int*)  (base + 51400704);       // 200,704
    int*   tmp      = (int*)  (base + 51601408);       // 200,704 (slots 50000+ reused as scan scratch)
    int*   sorted_e = (int*)  (base + 51802112);       // 2,000,000
    f16*   latW16   = (f16*)  (base + 53802112);       // 65,536
    f16*   Hh1      = (f16*)  (base + 53867648);       // 25,600,000
    f16*   Hh2      = (f16*)  (base + 79467648);
    f16*   Nh       = (f16*)  (base + 105067648);
    f16*   packs    = (f16*)  (base + 130667648);
    f16* Wfd  = packs;            // 98,304 halfs (K=384)
    f16* Whi  = Wfd  + 98304;
    f16* Whj  = Whi  + 65536;
    f16* We2  = Whj  + 65536;
    f16* Wn1h = We2  + 65536;
    f16* Wn1a = Wn1h + 65536;
    f16* Wn2  = Wn1a + 65536;     // ends at byte 131,650,688
    if (ws_size < (size_t)131650688) return;

    int* partials = tmp + 50000;  // 49 ints (unused tail of tmp)
    int* blkbase  = tmp + 50080;  // 49 ints

    // zero aggsum + cnt + off + tmp
    hipMemsetAsync(base, 0, (size_t)51802112, stream);

    // fused: 7 weight packs + latW + histogram
    prep_fused<<<2322, 256, 0, stream>>>(
        eW1, eW2, nW1, nW2, Wfd, Whi, Whj, We2, Wn1h, Wn1a, Wn2,
        lattices, eb1, latW16, edge_index, cnt);

    scan_part<<<49, 1024, 0, stream>>>(cnt, off, partials);
    scan_tops<<<1, 64, 0, stream>>>(partials, blkbase);
    pos_kernel<<<(E_EDGES + 255) / 256, 256, 0, stream>>>(edge_index, off, blkbase, tmp, sorted_e);

    ln_gemm_kernel<<<(N_NODES + 63) / 64, 256, 0, stream>>>(
        h, ln_gamma, ln_beta, Whi, Whj, Wn1h, Hh1, Hh2, Nh);

    edge_kernel<<<(E_EDGES + 31) / 32, 256, 0, stream>>>(
        sorted_e, edge_index, edge2graph, frac_diff, Hh1, Hh2, latW16, Wfd, We2, eb2, aggsum);

    node_post_kernel<<<(N_NODES + 63) / 64, 256, 0, stream>>>(
        aggsum, cnt, Nh, Wn1a, Wn2, nb1, nb2, h, out);
}

// Round 9
// 605.173 us; speedup vs baseline: 1.0134x; 1.0134x over previous
//
#include <hip/hip_runtime.h>
#include <hip/hip_bf16.h>
#include <math.h>

// Problem constants
#define N_NODES 50000
#define E_EDGES 500000
#define G_GRAPHS 128
#define N_PAD 50176   // 196*256 = 49*1024, padded node count for scan
// H = 256, NF = 64, EDGE_IN = 905 (rows: hi 0..255 | hj 256..511 | lat 512..520 | fd 521..904)

typedef _Float16 f16;
typedef _Float16 half8 __attribute__((ext_vector_type(8)));
typedef _Float16 half4 __attribute__((ext_vector_type(4)));
typedef float f32x4 __attribute__((ext_vector_type(4)));

// silu via v_rcp: avoids the precise-divide expansion (~9 instrs) of 1.0f/x
__device__ __forceinline__ float fast_silu(float x) {
    return x * __builtin_amdgcn_rcpf(1.0f + __expf(-x));
}

// ---------------------------------------------------------------------------
// Pack helper (device): [K x 256] row-major fp32 -> MFMA fragment-linear f16.
// chunk (nb, kstep): lane holds W[k=kstep*32+(lane>>4)*8+j][n=nb*16+(lane&15)].
// Serves BOTH as B-fragment (k,n) and as A-fragment (n,k) of W^T for the
// operand-swapped GEMMs.
// ---------------------------------------------------------------------------
__device__ __forceinline__ void pack_dev(const float* __restrict__ src,
                                         f16* __restrict__ dst, int Ksteps, int ltid) {
    int lane = ltid & 63;
    int chunk = ltid >> 6;
    int kstep = chunk % Ksteps;
    int nb = chunk / Ksteps;
    if (nb >= 16) return;
    int n = nb * 16 + (lane & 15);
    int k0 = kstep * 32 + (lane >> 4) * 8;
    f16* d = dst + (size_t)ltid * 8;
#pragma unroll
    for (int j = 0; j < 8; ++j)
        d[j] = (f16)src[(size_t)(k0 + j) * 256 + n];
}

// ---------------------------------------------------------------------------
// Fused prep: 7 weight packs + latW + edge histogram in ONE launch.
// ---------------------------------------------------------------------------
__global__ __launch_bounds__(256) void prep_fused(
    const float* __restrict__ eW1, const float* __restrict__ eW2,
    const float* __restrict__ nW1, const float* __restrict__ nW2,
    f16* __restrict__ Wfd, f16* __restrict__ Whi, f16* __restrict__ Whj,
    f16* __restrict__ We2, f16* __restrict__ Wn1h, f16* __restrict__ Wn1a,
    f16* __restrict__ Wn2,
    const float* __restrict__ lat, const float* __restrict__ eb1,
    f16* __restrict__ latW16,
    const int* __restrict__ ei, int* __restrict__ cnt)
{
    int b = blockIdx.x, t = threadIdx.x;
    if (b < 48)        { pack_dev(eW1 + 521 * 256, Wfd,  12, b * 256 + t); }
    else if (b < 80)   { pack_dev(eW1,             Whi,  8, (b - 48) * 256 + t); }
    else if (b < 112)  { pack_dev(eW1 + 256 * 256, Whj,  8, (b - 80) * 256 + t); }
    else if (b < 144)  { pack_dev(eW2,             We2,  8, (b - 112) * 256 + t); }
    else if (b < 176)  { pack_dev(nW1,             Wn1h, 8, (b - 144) * 256 + t); }
    else if (b < 208)  { pack_dev(nW1 + 256 * 256, Wn1a, 8, (b - 176) * 256 + t); }
    else if (b < 240)  { pack_dev(nW2,             Wn2,  8, (b - 208) * 256 + t); }
    else if (b < 368) {
        int g = b - 240, n = t;
        float l[9];
#pragma unroll
        for (int i = 0; i < 9; ++i) l[i] = lat[g * 9 + i];
        float acc = eb1[n];
#pragma unroll
        for (int i = 0; i < 3; ++i)
#pragma unroll
            for (int j = 0; j < 3; ++j) {
                float ip = l[i*3+0]*l[j*3+0] + l[i*3+1]*l[j*3+1] + l[i*3+2]*l[j*3+2];
                acc += ip * eW1[(size_t)(512 + i*3 + j) * 256 + n];
            }
        latW16[g * 256 + n] = (f16)acc;
    } else {
        int e = (b - 368) * 256 + t;
        if (e < E_EDGES) atomicAdd(cnt + ei[e], 1);
    }
}

// ---------------------------------------------------------------------------
// Parallel CSR scan: per-block exclusive scan + block totals, then a single
// wave scans the 49 totals. pos adds base[s>>10].
// ---------------------------------------------------------------------------
__global__ __launch_bounds__(1024) void scan_part(const int* __restrict__ cnt,
                                                  int* __restrict__ off,
                                                  int* __restrict__ partials) {
    __shared__ int wsum[16], wpre[16];
    int t = threadIdx.x, lane = t & 63, w = t >> 6;
    int c = blockIdx.x * 1024 + t;
    int v = cnt[c];
    int x = v;
#pragma unroll
    for (int d = 1; d < 64; d <<= 1) { int nn = __shfl_up(x, d); if (lane >= d) x += nn; }
    if (lane == 63) wsum[w] = x;
    __syncthreads();
    if (t < 16) {
        int s = wsum[t];
        int y = s;
#pragma unroll
        for (int d = 1; d < 16; d <<= 1) { int nn = __shfl_up(y, d, 16); if (t >= d) y += nn; }
        wpre[t] = y - s;
        if (t == 15) partials[blockIdx.x] = y;
    }
    __syncthreads();
    off[c] = wpre[w] + x - v;   // block-local exclusive
}

__global__ void scan_tops(const int* __restrict__ partials, int* __restrict__ base) {
    int t = threadIdx.x;   // 64 threads, 49 used
    int v = (t < 49) ? partials[t] : 0;
    int x = v;
#pragma unroll
    for (int d = 1; d < 64; d <<= 1) { int nn = __shfl_up(x, d); if (t >= d) x += nn; }
    if (t < 49) base[t] = x - v;   // exclusive
}

__global__ void pos_kernel(const int* __restrict__ ei, const int* __restrict__ off,
                           const int* __restrict__ base, int* __restrict__ tmp,
                           int* __restrict__ sorted_e) {
    int e = blockIdx.x * 256 + threadIdx.x;
    if (e >= E_EDGES) return;
    int s = ei[e];
    int p = off[s] + base[s >> 10] + atomicAdd(tmp + s, 1);
    sorted_e[p] = e;
}

// ---------------------------------------------------------------------------
// LayerNorm(h) then three OPERAND-SWAPPED GEMMs -> f16 outputs Hh1/Hh2/Nh.
// Load phase: 16-lanes-per-row mapping -> contiguous 256 B per-row loads;
// row stats via 4-level shfl_xor within the 16-lane group.
// ---------------------------------------------------------------------------
__global__ __launch_bounds__(256) void ln_gemm_kernel(
    const float* __restrict__ h, const float* __restrict__ gamma, const float* __restrict__ beta,
    const f16* __restrict__ Whi, const f16* __restrict__ Whj, const f16* __restrict__ Wn1,
    f16* __restrict__ Hh1, f16* __restrict__ Hh2, f16* __restrict__ Nh)
{
    __shared__ f16 Aln[64 * 264];
    int tid = threadIdx.x;
    int l15g = tid & 15;          // col-group lane
    int rq   = tid >> 4;          // 0..15: row slot within a round

    // hoist gamma/beta for this lane's cols: (l15g + 16*i) float4, i=0..3
    float4 gv[4], bv[4];
#pragma unroll
    for (int i = 0; i < 4; ++i) {
        gv[i] = ((const float4*)gamma)[l15g + 16*i];
        bv[i] = ((const float4*)beta )[l15g + 16*i];
    }

#pragma unroll
    for (int r4 = 0; r4 < 4; ++r4) {
        int rl = r4 * 16 + rq;                 // local row 0..63
        int row = blockIdx.x * 64 + rl;
        int rowc = min(row, N_NODES - 1);
        const float4* hp4 = (const float4*)(h + (size_t)rowc * 256);
        float4 xv[4];
        float s = 0.f, ss = 0.f;
#pragma unroll
        for (int i = 0; i < 4; ++i) {
            float4 x = hp4[l15g + 16*i];
            xv[i] = x;
            s  += x.x + x.y + x.z + x.w;
            ss += x.x*x.x + x.y*x.y + x.z*x.z + x.w*x.w;
        }
#pragma unroll
        for (int m = 1; m < 16; m <<= 1) {
            s  += __shfl_xor(s,  m);
            ss += __shfl_xor(ss, m);
        }
        float mean = s * (1.f / 256.f);
        float var  = ss * (1.f / 256.f) - mean * mean;
        float rstd = rsqrtf(var + 1e-5f);
#pragma unroll
        for (int i = 0; i < 4; ++i) {
            half4 o;
            o[0] = (f16)((xv[i].x - mean) * rstd * gv[i].x + bv[i].x);
            o[1] = (f16)((xv[i].y - mean) * rstd * gv[i].y + bv[i].y);
            o[2] = (f16)((xv[i].z - mean) * rstd * gv[i].z + bv[i].z);
            o[3] = (f16)((xv[i].w - mean) * rstd * gv[i].w + bv[i].w);
            *(half4*)(Aln + rl * 264 + (l15g + 16*i) * 4) = o;
        }
    }
    __syncthreads();

    int lane = tid & 63, w = tid >> 6;
    int l15 = lane & 15, q = lane >> 4;
    const f16* Ws[3] = {Whi, Whj, Wn1};
    f16* Os[3] = {Hh1, Hh2, Nh};
    const f32x4 z4 = {0.f, 0.f, 0.f, 0.f};

    for (int widx = 0; widx < 3; ++widx) {
        f32x4 acc[4][4];   // [mi Hcol-block][g node-group]
#pragma unroll
        for (int a = 0; a < 4; ++a)
#pragma unroll
            for (int b = 0; b < 4; ++b) acc[a][b] = z4;
        const f16* W = Ws[widx];
        for (int ks = 0; ks < 8; ++ks) {
            half8 bfr[4];
#pragma unroll
            for (int g = 0; g < 4; ++g)
                bfr[g] = *(const half8*)(Aln + (g*16 + l15) * 264 + ks*32 + q*8);
#pragma unroll
            for (int mi = 0; mi < 4; ++mi) {
                half8 afr = *(const half8*)(W + ((size_t)((w*4 + mi)*8 + ks) * 64 + lane) * 8);
#pragma unroll
                for (int g = 0; g < 4; ++g)
                    acc[mi][g] = __builtin_amdgcn_mfma_f32_16x16x32_f16(afr, bfr[g], acc[mi][g], 0, 0, 0);
            }
        }
        f16* O = Os[widx];
#pragma unroll
        for (int g = 0; g < 4; ++g) {
            int orow = blockIdx.x * 64 + g*16 + l15;
            if (orow < N_NODES) {
#pragma unroll
                for (int mi = 0; mi < 4; ++mi) {
                    int hc0 = (w*4 + mi) * 16 + q * 4;
                    half4 hv;
                    hv[0] = (f16)acc[mi][g][0]; hv[1] = (f16)acc[mi][g][1];
                    hv[2] = (f16)acc[mi][g][2]; hv[3] = (f16)acc[mi][g][3];
                    *(half4*)(O + (size_t)orow * 256 + hc0) = hv;
                }
            }
        }
    }
}

// ---------------------------------------------------------------------------
// Edge kernel v14: REVERT to the R6/v11 configuration (best measured: 320 us,
// FETCH 242 / WRITE 64) -- bufB 18.4 KB e2 tile [Hcol][36], b64 segred,
// LDS 36,352 -> 4 blocks/CU. v12/v13's 5-block variant inflated L2 miss
// traffic (+47 FETCH / +109 WRITE MB) and regressed.
// NEW: Hh2[dst] gathers use __builtin_nontemporal_load. Hh2 is a 25.6 MB
// array gathered randomly (256 MB raw) -- near-zero L2 reuse per line, yet
// the fills evict high-reuse weight (320 KB/block) and aggsum atomic lines.
// nt marks them evict-first, preserving L2 for data with reuse. Hh1 (sorted
// src -> consecutive-edge reuse) and latW (64 KB, hot) stay cached.
// ---------------------------------------------------------------------------
__global__ __launch_bounds__(256, 4) void edge_kernel(
    const int* __restrict__ sorted_e,
    const int* __restrict__ edge_index, const int* __restrict__ edge2graph,
    const float* __restrict__ frac_diff,
    const f16* __restrict__ Hh1, const f16* __restrict__ Hh2, const f16* __restrict__ latW16,
    const f16* __restrict__ Wfd, const f16* __restrict__ We2, const float* __restrict__ eb2,
    float* __restrict__ aggsum)
{
    __shared__ f16 bufA[32 * 264];   // 16.9 KB: R tile -> e1 tile, row-major [edge][264]
    __shared__ f16 bufB[9216];       // 18.4 KB: frag pass window (12.3) / e2 tile [256][36]
    __shared__ float frac_s[32][4];
    __shared__ int src_s[32], dst_s[32], g_s[32], srcr[32];
    int tid = threadIdx.x;
    int e0 = blockIdx.x * 32;

    if (tid < 32) {
        int slot = e0 + tid;
        int e = (slot < E_EDGES) ? sorted_e[slot] : -1;
        int ec = e < 0 ? 0 : e;
        int sv = edge_index[ec];
        src_s[tid] = sv;
        dst_s[tid] = edge_index[E_EDGES + ec];
        g_s[tid]   = edge2graph[ec];
        srcr[tid]  = (e < 0) ? -1 : sv;
        frac_s[tid][0] = frac_diff[(size_t)ec * 3 + 0];
        frac_s[tid][1] = frac_diff[(size_t)ec * 3 + 1];
        frac_s[tid][2] = frac_diff[(size_t)ec * 3 + 2];
    }
    __syncthreads();   // B1: indices + frac ready

    // Stage one pass: 384 units (row 32, z 3, q2 4), <=2 per thread.
    // Unit writes sin frag slot z, cos frag slot z+3, lane (row&15)+16*q2,
    // covering k = fb*32 + q2*8 + j (j=0..7) via 8 rotation steps from a
    // direct-trig seed at k0 = fb*32 + q2*8.
    auto stage_pass = [&](int p) {
#pragma unroll
        for (int uu = 0; uu < 2; ++uu) {
            int u = tid + uu * 256;
            if (u < 384) {
                int row = u & 31;
                int zz = u >> 5;           // 0..11 = z*4 + q2
                int z = zz >> 2, q2 = zz & 3;
                int kg = p * 3 + z;
                int d = kg >> 1, fb = kg & 1;
                float x = frac_s[row][d];
                float c1 = __builtin_amdgcn_cosf(x);
                float s1 = __builtin_amdgcn_sinf(x);
                float t0 = x * (float)(fb * 32 + q2 * 8);
                float rev = t0 - floorf(t0);
                float s = __builtin_amdgcn_sinf(rev);
                float c = __builtin_amdgcn_cosf(rev);
                f16 avs[8], avc[8];
#pragma unroll
                for (int j = 0; j < 8; ++j) {
                    avs[j] = (f16)s; avc[j] = (f16)c;
                    float ns = s * c1 + c * s1;
                    float nc = c * c1 - s * s1;
                    s = ns; c = nc;
                }
                int mb = row >> 4;
                int lslot = (row & 15) + 16 * q2;
                *(half8*)(bufB + (((z    ) * 2 + mb) * 64 + lslot) * 8) = *(half8*)avs;
                *(half8*)(bufB + (((z + 3) * 2 + mb) * 64 + lslot) * 8) = *(half8*)avc;
            }
        }
    };

    // ---- R-fill: thread owns row m = tid>>3; chunks cc = (tid&7) + 8*i.
    {
        int m = tid >> 3, c0 = tid & 7;
        const f16* pa = Hh1    + (size_t)src_s[m] * 256 + c0 * 8;
        const f16* pb = Hh2    + (size_t)dst_s[m] * 256 + c0 * 8;
        const f16* pc = latW16 + (size_t)g_s[m]   * 256 + c0 * 8;
        f16* pd = bufA + m * 264 + c0 * 8;
#pragma unroll
        for (int i = 0; i < 4; ++i) {
            half8 a = *(const half8*)(pa + i * 64);
            half8 b = __builtin_nontemporal_load((const half8*)(pb + i * 64));
            half8 c = *(const half8*)(pc + i * 64);
            *(half8*)(pd + i * 64) = a + b + c;
        }
    }
    stage_pass(0);
    __syncthreads();   // B2: R tile + pass-0 frags ready

    int lane = tid & 63, w = tid >> 6;
    int l15 = lane & 15, q = lane >> 4;

    // ---- swapped GEMM1: e1^T[Hcol][edge] = Wfd^T @ fd^T + R^T.
    f32x4 acc[4][2];
#pragma unroll
    for (int mi = 0; mi < 4; ++mi)
#pragma unroll
        for (int g = 0; g < 2; ++g) {
            int edge = g * 16 + l15;
            int hc0 = (w*4 + mi) * 16 + q * 4;
            half4 rv = *(const half4*)(bufA + edge * 264 + hc0);
            f32x4 a;
            a[0] = (float)rv[0]; a[1] = (float)rv[1];
            a[2] = (float)rv[2]; a[3] = (float)rv[3];
            acc[mi][g] = a;
        }

#pragma unroll
    for (int p = 0; p < 2; ++p) {
        if (p == 1) {
            __syncthreads();   // B2b: pass-0 frag reads done
            stage_pass(1);
            __syncthreads();   // B2c: pass-1 frags ready
        }
#pragma unroll
        for (int z = 0; z < 3; ++z) {
            int kg = p * 3 + z;
            half8 aS[4], aC[4];
#pragma unroll
            for (int mi = 0; mi < 4; ++mi) {
                int mblk = w * 4 + mi;
                aS[mi] = *(const half8*)(Wfd + ((size_t)(mblk*12 + kg)     * 64 + lane) * 8);
                aC[mi] = *(const half8*)(Wfd + ((size_t)(mblk*12 + kg + 6) * 64 + lane) * 8);
            }
#pragma unroll
            for (int g = 0; g < 2; ++g) {
                half8 bS = *(const half8*)(bufB + (((z    ) * 2 + g) * 64 + lane) * 8);
                half8 bC = *(const half8*)(bufB + (((z + 3) * 2 + g) * 64 + lane) * 8);
#pragma unroll
                for (int mi = 0; mi < 4; ++mi) {
                    acc[mi][g] = __builtin_amdgcn_mfma_f32_16x16x32_f16(aS[mi], bS, acc[mi][g], 0, 0, 0);
                    acc[mi][g] = __builtin_amdgcn_mfma_f32_16x16x32_f16(aC[mi], bC, acc[mi][g], 0, 0, 0);
                }
            }
        }
    }

    // ---- epilogue 1: silu -> e1 row-major [edge][264] (owner-exclusive)
#pragma unroll
    for (int mi = 0; mi < 4; ++mi)
#pragma unroll
        for (int g = 0; g < 2; ++g) {
            int edge = g * 16 + l15;
            int hc0 = (w*4 + mi) * 16 + q * 4;
            half4 tv;
            tv[0] = (f16)fast_silu(acc[mi][g][0]);
            tv[1] = (f16)fast_silu(acc[mi][g][1]);
            tv[2] = (f16)fast_silu(acc[mi][g][2]);
            tv[3] = (f16)fast_silu(acc[mi][g][3]);
            *(half4*)(bufA + edge * 264 + hc0) = tv;
        }
    __syncthreads();   // B3: e1 tile ready (also: all pass-1 frag reads done)

    // ---- swapped GEMM2: e2^T = We2^T @ e1^T
    f32x4 acc2[4][2];
    const f32x4 z4 = {0.f, 0.f, 0.f, 0.f};
#pragma unroll
    for (int a = 0; a < 4; ++a)
#pragma unroll
        for (int b = 0; b < 2; ++b) acc2[a][b] = z4;
#pragma unroll
    for (int ks = 0; ks < 8; ++ks) {
        half8 bfr[2];
#pragma unroll
        for (int g = 0; g < 2; ++g)
            bfr[g] = *(const half8*)(bufA + (g*16 + l15) * 264 + ks*32 + q*8);
#pragma unroll
        for (int mi = 0; mi < 4; ++mi) {
            half8 afr = *(const half8*)(We2 + ((size_t)((w*4 + mi)*8 + ks) * 64 + lane) * 8);
#pragma unroll
            for (int g = 0; g < 2; ++g)
                acc2[mi][g] = __builtin_amdgcn_mfma_f32_16x16x32_f16(afr, bfr[g], acc2[mi][g], 0, 0, 0);
        }
    }

    // ---- epilogue 2: silu(+eb2) -> e2 tile [Hcol][edge pad36] f16 in bufB
    // (frags dead since GEMM1; B3 covers the WAR). Invalid edges -> 0.
    {
        float msk[2];
#pragma unroll
        for (int g = 0; g < 2; ++g)
            msk[g] = (srcr[g*16 + l15] >= 0) ? 1.f : 0.f;
#pragma unroll
        for (int mi = 0; mi < 4; ++mi) {
            int hc0 = (w*4 + mi) * 16 + q * 4;
            float4 e4 = *(const float4*)(eb2 + hc0);
#pragma unroll
            for (int g = 0; g < 2; ++g) {
                int edge = g * 16 + l15;
                bufB[(hc0 + 0) * 36 + edge] = (f16)(fast_silu(acc2[mi][g][0] + e4.x) * msk[g]);
                bufB[(hc0 + 1) * 36 + edge] = (f16)(fast_silu(acc2[mi][g][1] + e4.y) * msk[g]);
                bufB[(hc0 + 2) * 36 + edge] = (f16)(fast_silu(acc2[mi][g][2] + e4.z) * msk[g]);
                bufB[(hc0 + 3) * 36 + edge] = (f16)(fast_silu(acc2[mi][g][3] + e4.w) * msk[g]);
            }
        }
    }
    __syncthreads();   // B4: e2 tile ready

    // ---- segmented reduction: thread t owns Hcol t; edges contiguous -> b64.
    {
        int t = tid;
        float run = 0.f;
        int cur = srcr[0];
#pragma unroll
        for (int m4 = 0; m4 < 8; ++m4) {
            half4 vv = *(const half4*)(bufB + t * 36 + m4 * 4);
#pragma unroll
            for (int jj = 0; jj < 4; ++jj) {
                int mm = m4 * 4 + jj;
                int s = srcr[mm];
                float v = (float)vv[jj];
                if (s != cur) {
                    if (cur >= 0) atomicAdd(aggsum + (size_t)cur * 256 + t, run);
                    cur = s; run = v;
                } else run += v;
            }
        }
        if (cur >= 0) atomicAdd(aggsum + (size_t)cur * 256 + t, run);
    }
}

// ---------------------------------------------------------------------------
// Node post (operand-swapped): agg = aggsum/max(cnt,1);
// t = silu(Nh + agg@Wn1a + nb1); out = h + silu(t@Wn2 + nb2).
// Load phase: linear lane-major mapping -> 1 KB contiguous per instruction.
// ---------------------------------------------------------------------------
__global__ __launch_bounds__(256) void node_post_kernel(
    const float* __restrict__ aggsum, const int* __restrict__ cnt,
    const f16* __restrict__ Nh, const f16* __restrict__ Wn1a, const f16* __restrict__ Wn2,
    const float* __restrict__ nb1, const float* __restrict__ nb2,
    const float* __restrict__ h, float* __restrict__ out)
{
    __shared__ f16 T[64 * 264];
    int tid = threadIdx.x;
    int lane = tid & 63, w = tid >> 6;
    {
#pragma unroll
        for (int i = 0; i < 16; ++i) {
            int rl = w + 4 * i;                 // local row 0..63, wave-uniform
            int row = blockIdx.x * 64 + rl;
            int rowc = min(row, N_NODES - 1);
            float inv = 1.f / fmaxf((float)cnt[rowc], 1.f);
            float4 x = ((const float4*)(aggsum + (size_t)rowc * 256))[lane];
            half4 av;
            av[0] = (f16)(x.x * inv);
            av[1] = (f16)(x.y * inv);
            av[2] = (f16)(x.z * inv);
            av[3] = (f16)(x.w * inv);
            *(half4*)(T + rl * 264 + lane * 4) = av;
        }
    }
    __syncthreads();

    int l15 = lane & 15, q = lane >> 4;
    const f32x4 z4 = {0.f, 0.f, 0.f, 0.f};

    // GEMM1 swapped: acc[mi][g], A = Wn1a frag, B = T rows (agg)
    f32x4 acc[4][4];
#pragma unroll
    for (int a = 0; a < 4; ++a)
#pragma unroll
        for (int b = 0; b < 4; ++b) acc[a][b] = z4;
    for (int ks = 0; ks < 8; ++ks) {
        half8 bfr[4];
#pragma unroll
        for (int g = 0; g < 4; ++g)
            bfr[g] = *(const half8*)(T + (g*16 + l15) * 264 + ks*32 + q*8);
#pragma unroll
        for (int mi = 0; mi < 4; ++mi) {
            half8 afr = *(const half8*)(Wn1a + ((size_t)((w*4 + mi)*8 + ks) * 64 + lane) * 8);
#pragma unroll
            for (int g = 0; g < 4; ++g)
                acc[mi][g] = __builtin_amdgcn_mfma_f32_16x16x32_f16(afr, bfr[g], acc[mi][g], 0, 0, 0);
        }
    }
    __syncthreads();   // all T reads done

    // t = silu(acc + Nh + nb1) -> T'[node][hc0..3] half4 writes
#pragma unroll
    for (int mi = 0; mi < 4; ++mi) {
        int hc0 = (w*4 + mi) * 16 + q * 4;
        f32x4 b1v = *(const f32x4*)(nb1 + hc0);
#pragma unroll
        for (int g = 0; g < 4; ++g) {
            int nodeg = blockIdx.x * 64 + g*16 + l15;
            int orc = min(nodeg, N_NODES - 1);
            half4 nh4 = *(const half4*)(Nh + (size_t)orc * 256 + hc0);
            half4 tv;
            tv[0] = (f16)fast_silu(acc[mi][g][0] + (float)nh4[0] + b1v[0]);
            tv[1] = (f16)fast_silu(acc[mi][g][1] + (float)nh4[1] + b1v[1]);
            tv[2] = (f16)fast_silu(acc[mi][g][2] + (float)nh4[2] + b1v[2]);
            tv[3] = (f16)fast_silu(acc[mi][g][3] + (float)nh4[3] + b1v[3]);
            *(half4*)(T + (g*16 + l15) * 264 + hc0) = tv;
        }
    }
    __syncthreads();

    // GEMM2 swapped: A = Wn2 frag, B = T' rows
    f32x4 acc2[4][4];
#pragma unroll
    for (int a = 0; a < 4; ++a)
#pragma unroll
        for (int b = 0; b < 4; ++b) acc2[a][b] = z4;
    for (int ks = 0; ks < 8; ++ks) {
        half8 bfr[4];
#pragma unroll
        for (int g = 0; g < 4; ++g)
            bfr[g] = *(const half8*)(T + (g*16 + l15) * 264 + ks*32 + q*8);
#pragma unroll
        for (int mi = 0; mi < 4; ++mi) {
            half8 afr = *(const half8*)(Wn2 + ((size_t)((w*4 + mi)*8 + ks) * 64 + lane) * 8);
#pragma unroll
            for (int g = 0; g < 4; ++g)
                acc2[mi][g] = __builtin_amdgcn_mfma_f32_16x16x32_f16(afr, bfr[g], acc2[mi][g], 0, 0, 0);
        }
    }

    // out = h + silu(acc2 + nb2) -> float4 stores
#pragma unroll
    for (int g = 0; g < 4; ++g) {
        int orow = blockIdx.x * 64 + g*16 + l15;
        if (orow < N_NODES) {
#pragma unroll
            for (int mi = 0; mi < 4; ++mi) {
                int hc0 = (w*4 + mi) * 16 + q * 4;
                f32x4 b2v = *(const f32x4*)(nb2 + hc0);
                f32x4 hv  = *(const f32x4*)(h + (size_t)orow * 256 + hc0);
                f32x4 ov;
                ov[0] = hv[0] + fast_silu(acc2[mi][g][0] + b2v[0]);
                ov[1] = hv[1] + fast_silu(acc2[mi][g][1] + b2v[1]);
                ov[2] = hv[2] + fast_silu(acc2[mi][g][2] + b2v[2]);
                ov[3] = hv[3] + fast_silu(acc2[mi][g][3] + b2v[3]);
                *(f32x4*)(out + (size_t)orow * 256 + hc0) = ov;
            }
        }
    }
}

// ---------------------------------------------------------------------------
extern "C" void kernel_launch(void* const* d_in, const int* in_sizes, int n_in,
                              void* d_out, int out_size, void* d_ws, size_t ws_size,
                              hipStream_t stream) {
    const float* h          = (const float*)d_in[0];
    const float* lattices   = (const float*)d_in[2];
    const int*   edge_index = (const int*)d_in[3];
    const int*   edge2graph = (const int*)d_in[4];
    const float* frac_diff  = (const float*)d_in[5];
    const float* ln_gamma   = (const float*)d_in[6];
    const float* ln_beta    = (const float*)d_in[7];
    const float* eW1        = (const float*)d_in[8];
    const float* eb1        = (const float*)d_in[9];
    const float* eW2        = (const float*)d_in[10];
    const float* eb2        = (const float*)d_in[11];
    const float* nW1        = (const float*)d_in[12];
    const float* nb1        = (const float*)d_in[13];
    const float* nW2        = (const float*)d_in[14];
    const float* nb2        = (const float*)d_in[15];
    float* out = (float*)d_out;
    char* base = (char*)d_ws;

    // workspace layout (byte offsets)
    float* aggsum   = (float*)(base + 0);              // 51,200,000 B
    int*   cnt      = (int*)  (base + 51200000);       // 200,704
    int*   off      = (int*)  (base + 51400704);       // 200,704
    int*   tmp      = (int*)  (base + 51601408);       // 200,704 (slots 50000+ reused as scan scratch)
    int*   sorted_e = (int*)  (base + 51802112);       // 2,000,000
    f16*   latW16   = (f16*)  (base + 53802112);       // 65,536
    f16*   Hh1      = (f16*)  (base + 53867648);       // 25,600,000
    f16*   Hh2      = (f16*)  (base + 79467648);
    f16*   Nh       = (f16*)  (base + 105067648);
    f16*   packs    = (f16*)  (base + 130667648);
    f16* Wfd  = packs;            // 98,304 halfs (K=384)
    f16* Whi  = Wfd  + 98304;
    f16* Whj  = Whi  + 65536;
    f16* We2  = Whj  + 65536;
    f16* Wn1h = We2  + 65536;
    f16* Wn1a = Wn1h + 65536;
    f16* Wn2  = Wn1a + 65536;     // ends at byte 131,650,688
    if (ws_size < (size_t)131650688) return;

    int* partials = tmp + 50000;  // 49 ints (unused tail of tmp)
    int* blkbase  = tmp + 50080;  // 49 ints

    // zero aggsum + cnt + off + tmp
    hipMemsetAsync(base, 0, (size_t)51802112, stream);

    // fused: 7 weight packs + latW + histogram
    prep_fused<<<2322, 256, 0, stream>>>(
        eW1, eW2, nW1, nW2, Wfd, Whi, Whj, We2, Wn1h, Wn1a, Wn2,
        lattices, eb1, latW16, edge_index, cnt);

    scan_part<<<49, 1024, 0, stream>>>(cnt, off, partials);
    scan_tops<<<1, 64, 0, stream>>>(partials, blkbase);
    pos_kernel<<<(E_EDGES + 255) / 256, 256, 0, stream>>>(edge_index, off, blkbase, tmp, sorted_e);

    ln_gemm_kernel<<<(N_NODES + 63) / 64, 256, 0, stream>>>(
        h, ln_gamma, ln_beta, Whi, Whj, Wn1h, Hh1, Hh2, Nh);

    edge_kernel<<<(E_EDGES + 31) / 32, 256, 0, stream>>>(
        sorted_e, edge_index, edge2graph, frac_diff, Hh1, Hh2, latW16, Wfd, We2, eb2, aggsum);

    node_post_kernel<<<(N_NODES + 63) / 64, 256, 0, stream>>>(
        aggsum, cnt, Nh, Wn1a, Wn2, nb1, nb2, h, out);
}

// Round 10
// 590.723 us; speedup vs baseline: 1.0382x; 1.0245x over previous
//
#include <hip/hip_runtime.h>
#include <hip/hip_bf16.h>
#include <math.h>

// Problem constants
#define N_NODES 50000
#define E_EDGES 500000
#define G_GRAPHS 128
#define N_PAD 50176   // 196*256 = 49*1024, padded node count for scan
#define POS_BLOCKS 1954   // ceil(E/256)
#define LN_BLOCKS 782     // ceil(N/64)
// H = 256, NF = 64, EDGE_IN = 905 (rows: hi 0..255 | hj 256..511 | lat 512..520 | fd 521..904)

typedef _Float16 f16;
typedef _Float16 half8 __attribute__((ext_vector_type(8)));
typedef _Float16 half4 __attribute__((ext_vector_type(4)));
typedef float f32x4 __attribute__((ext_vector_type(4)));

// silu via v_rcp: avoids the precise-divide expansion (~9 instrs) of 1.0f/x
__device__ __forceinline__ float fast_silu(float x) {
    return x * __builtin_amdgcn_rcpf(1.0f + __expf(-x));
}

// ---------------------------------------------------------------------------
// Pack helper (device): [K x 256] row-major fp32 -> MFMA fragment-linear f16.
// chunk (nb, kstep): lane holds W[k=kstep*32+(lane>>4)*8+j][n=nb*16+(lane&15)].
// Serves BOTH as B-fragment (k,n) and as A-fragment (n,k) of W^T for the
// operand-swapped GEMMs.
// ---------------------------------------------------------------------------
__device__ __forceinline__ void pack_dev(const float* __restrict__ src,
                                         f16* __restrict__ dst, int Ksteps, int ltid) {
    int lane = ltid & 63;
    int chunk = ltid >> 6;
    int kstep = chunk % Ksteps;
    int nb = chunk / Ksteps;
    if (nb >= 16) return;
    int n = nb * 16 + (lane & 15);
    int k0 = kstep * 32 + (lane >> 4) * 8;
    f16* d = dst + (size_t)ltid * 8;
#pragma unroll
    for (int j = 0; j < 8; ++j)
        d[j] = (f16)src[(size_t)(k0 + j) * 256 + n];
}

// ---------------------------------------------------------------------------
// Fused prep: 7 weight packs + latW + edge histogram in ONE launch.
// ---------------------------------------------------------------------------
__global__ __launch_bounds__(256) void prep_fused(
    const float* __restrict__ eW1, const float* __restrict__ eW2,
    const float* __restrict__ nW1, const float* __restrict__ nW2,
    f16* __restrict__ Wfd, f16* __restrict__ Whi, f16* __restrict__ Whj,
    f16* __restrict__ We2, f16* __restrict__ Wn1h, f16* __restrict__ Wn1a,
    f16* __restrict__ Wn2,
    const float* __restrict__ lat, const float* __restrict__ eb1,
    f16* __restrict__ latW16,
    const int* __restrict__ ei, int* __restrict__ cnt)
{
    int b = blockIdx.x, t = threadIdx.x;
    if (b < 48)        { pack_dev(eW1 + 521 * 256, Wfd,  12, b * 256 + t); }
    else if (b < 80)   { pack_dev(eW1,             Whi,  8, (b - 48) * 256 + t); }
    else if (b < 112)  { pack_dev(eW1 + 256 * 256, Whj,  8, (b - 80) * 256 + t); }
    else if (b < 144)  { pack_dev(eW2,             We2,  8, (b - 112) * 256 + t); }
    else if (b < 176)  { pack_dev(nW1,             Wn1h, 8, (b - 144) * 256 + t); }
    else if (b < 208)  { pack_dev(nW1 + 256 * 256, Wn1a, 8, (b - 176) * 256 + t); }
    else if (b < 240)  { pack_dev(nW2,             Wn2,  8, (b - 208) * 256 + t); }
    else if (b < 368) {
        int g = b - 240, n = t;
        float l[9];
#pragma unroll
        for (int i = 0; i < 9; ++i) l[i] = lat[g * 9 + i];
        float acc = eb1[n];
#pragma unroll
        for (int i = 0; i < 3; ++i)
#pragma unroll
            for (int j = 0; j < 3; ++j) {
                float ip = l[i*3+0]*l[j*3+0] + l[i*3+1]*l[j*3+1] + l[i*3+2]*l[j*3+2];
                acc += ip * eW1[(size_t)(512 + i*3 + j) * 256 + n];
            }
        latW16[g * 256 + n] = (f16)acc;
    } else {
        int e = (b - 368) * 256 + t;
        if (e < E_EDGES) atomicAdd(cnt + ei[e], 1);
    }
}

// ---------------------------------------------------------------------------
// Parallel CSR scan: per-block exclusive scan + block totals, then a single
// wave scans the 49 totals. pos adds base[s>>10].
// ---------------------------------------------------------------------------
__global__ __launch_bounds__(1024) void scan_part(const int* __restrict__ cnt,
                                                  int* __restrict__ off,
                                                  int* __restrict__ partials) {
    __shared__ int wsum[16], wpre[16];
    int t = threadIdx.x, lane = t & 63, w = t >> 6;
    int c = blockIdx.x * 1024 + t;
    int v = cnt[c];
    int x = v;
#pragma unroll
    for (int d = 1; d < 64; d <<= 1) { int nn = __shfl_up(x, d); if (lane >= d) x += nn; }
    if (lane == 63) wsum[w] = x;
    __syncthreads();
    if (t < 16) {
        int s = wsum[t];
        int y = s;
#pragma unroll
        for (int d = 1; d < 16; d <<= 1) { int nn = __shfl_up(y, d, 16); if (t >= d) y += nn; }
        wpre[t] = y - s;
        if (t == 15) partials[blockIdx.x] = y;
    }
    __syncthreads();
    off[c] = wpre[w] + x - v;   // block-local exclusive
}

__global__ void scan_tops(const int* __restrict__ partials, int* __restrict__ base) {
    int t = threadIdx.x;   // 64 threads, 49 used
    int v = (t < 49) ? partials[t] : 0;
    int x = v;
#pragma unroll
    for (int d = 1; d < 64; d <<= 1) { int nn = __shfl_up(x, d); if (t >= d) x += nn; }
    if (t < 49) base[t] = x - v;   // exclusive
}

// ---------------------------------------------------------------------------
// FUSED pos + ln_gemm: the CSR position-scatter (latency-bound) and the
// LayerNorm+3-GEMM kernel (MFMA-bound) are mutually independent; running
// them in one launch overlaps the scatter's memory latency with compute.
// Blocks [0, POS_BLOCKS): pos. Blocks [POS_BLOCKS, POS_BLOCKS+LN_BLOCKS): ln.
// ---------------------------------------------------------------------------
__global__ __launch_bounds__(256) void pos_ln_kernel(
    const int* __restrict__ ei, const int* __restrict__ off,
    const int* __restrict__ base, int* __restrict__ tmp,
    int* __restrict__ sorted_e,
    const float* __restrict__ h, const float* __restrict__ gamma, const float* __restrict__ beta,
    const f16* __restrict__ Whi, const f16* __restrict__ Whj, const f16* __restrict__ Wn1,
    f16* __restrict__ Hh1, f16* __restrict__ Hh2, f16* __restrict__ Nh)
{
    __shared__ f16 Aln[64 * 264];
    int tid = threadIdx.x;

    if (blockIdx.x < POS_BLOCKS) {
        int e = blockIdx.x * 256 + tid;
        if (e < E_EDGES) {
            int s = ei[e];
            int p = off[s] + base[s >> 10] + atomicAdd(tmp + s, 1);
            sorted_e[p] = e;
        }
        return;
    }
    int lb = blockIdx.x - POS_BLOCKS;

    // ---- LayerNorm load phase: 16-lanes-per-row mapping, contiguous loads.
    int l15g = tid & 15;          // col-group lane
    int rq   = tid >> 4;          // 0..15: row slot within a round

    float4 gv[4], bv[4];
#pragma unroll
    for (int i = 0; i < 4; ++i) {
        gv[i] = ((const float4*)gamma)[l15g + 16*i];
        bv[i] = ((const float4*)beta )[l15g + 16*i];
    }

#pragma unroll
    for (int r4 = 0; r4 < 4; ++r4) {
        int rl = r4 * 16 + rq;                 // local row 0..63
        int row = lb * 64 + rl;
        int rowc = min(row, N_NODES - 1);
        const float4* hp4 = (const float4*)(h + (size_t)rowc * 256);
        float4 xv[4];
        float s = 0.f, ss = 0.f;
#pragma unroll
        for (int i = 0; i < 4; ++i) {
            float4 x = hp4[l15g + 16*i];
            xv[i] = x;
            s  += x.x + x.y + x.z + x.w;
            ss += x.x*x.x + x.y*x.y + x.z*x.z + x.w*x.w;
        }
#pragma unroll
        for (int m = 1; m < 16; m <<= 1) {
            s  += __shfl_xor(s,  m);
            ss += __shfl_xor(ss, m);
        }
        float mean = s * (1.f / 256.f);
        float var  = ss * (1.f / 256.f) - mean * mean;
        float rstd = rsqrtf(var + 1e-5f);
#pragma unroll
        for (int i = 0; i < 4; ++i) {
            half4 o;
            o[0] = (f16)((xv[i].x - mean) * rstd * gv[i].x + bv[i].x);
            o[1] = (f16)((xv[i].y - mean) * rstd * gv[i].y + bv[i].y);
            o[2] = (f16)((xv[i].z - mean) * rstd * gv[i].z + bv[i].z);
            o[3] = (f16)((xv[i].w - mean) * rstd * gv[i].w + bv[i].w);
            *(half4*)(Aln + rl * 264 + (l15g + 16*i) * 4) = o;
        }
    }
    __syncthreads();

    int lane = tid & 63, w = tid >> 6;
    int l15 = lane & 15, q = lane >> 4;
    const f16* Ws[3] = {Whi, Whj, Wn1};
    f16* Os[3] = {Hh1, Hh2, Nh};
    const f32x4 z4 = {0.f, 0.f, 0.f, 0.f};

    for (int widx = 0; widx < 3; ++widx) {
        f32x4 acc[4][4];   // [mi Hcol-block][g node-group]
#pragma unroll
        for (int a = 0; a < 4; ++a)
#pragma unroll
            for (int b = 0; b < 4; ++b) acc[a][b] = z4;
        const f16* W = Ws[widx];
        for (int ks = 0; ks < 8; ++ks) {
            half8 bfr[4];
#pragma unroll
            for (int g = 0; g < 4; ++g)
                bfr[g] = *(const half8*)(Aln + (g*16 + l15) * 264 + ks*32 + q*8);
#pragma unroll
            for (int mi = 0; mi < 4; ++mi) {
                half8 afr = *(const half8*)(W + ((size_t)((w*4 + mi)*8 + ks) * 64 + lane) * 8);
#pragma unroll
                for (int g = 0; g < 4; ++g)
                    acc[mi][g] = __builtin_amdgcn_mfma_f32_16x16x32_f16(afr, bfr[g], acc[mi][g], 0, 0, 0);
            }
        }
        f16* O = Os[widx];
#pragma unroll
        for (int g = 0; g < 4; ++g) {
            int orow = lb * 64 + g*16 + l15;
            if (orow < N_NODES) {
#pragma unroll
                for (int mi = 0; mi < 4; ++mi) {
                    int hc0 = (w*4 + mi) * 16 + q * 4;
                    half4 hv;
                    hv[0] = (f16)acc[mi][g][0]; hv[1] = (f16)acc[mi][g][1];
                    hv[2] = (f16)acc[mi][g][2]; hv[3] = (f16)acc[mi][g][3];
                    *(half4*)(O + (size_t)orow * 256 + hc0) = hv;
                }
            }
        }
    }
}

// ---------------------------------------------------------------------------
// Edge kernel v15 = exact R6/v11 configuration (best measured: 320 us).
// 4 blocks/CU (LDS 36,352), balanced 384-unit staging, bufB 18.4 KB e2 tile
// [Hcol][36] with b64 segred, plain (cached) Hh2 loads. R7-R9 A/Bs showed:
// 5 blocks/CU overflows the per-XCD gather footprint (128 blk x 32 KB = 4 MB
// = L2) -> +156 MB HBM traffic; XCD swizzle neutral; nt-loads on Hh2 raise
// gather latency (L1 bypass) for a small FETCH gain. This config is the
// measured optimum of that exploration.
// ---------------------------------------------------------------------------
__global__ __launch_bounds__(256, 4) void edge_kernel(
    const int* __restrict__ sorted_e,
    const int* __restrict__ edge_index, const int* __restrict__ edge2graph,
    const float* __restrict__ frac_diff,
    const f16* __restrict__ Hh1, const f16* __restrict__ Hh2, const f16* __restrict__ latW16,
    const f16* __restrict__ Wfd, const f16* __restrict__ We2, const float* __restrict__ eb2,
    float* __restrict__ aggsum)
{
    __shared__ f16 bufA[32 * 264];   // 16.9 KB: R tile -> e1 tile, row-major [edge][264]
    __shared__ f16 bufB[9216];       // 18.4 KB: frag pass window (12.3) / e2 tile [256][36]
    __shared__ float frac_s[32][4];
    __shared__ int src_s[32], dst_s[32], g_s[32], srcr[32];
    int tid = threadIdx.x;
    int e0 = blockIdx.x * 32;

    if (tid < 32) {
        int slot = e0 + tid;
        int e = (slot < E_EDGES) ? sorted_e[slot] : -1;
        int ec = e < 0 ? 0 : e;
        int sv = edge_index[ec];
        src_s[tid] = sv;
        dst_s[tid] = edge_index[E_EDGES + ec];
        g_s[tid]   = edge2graph[ec];
        srcr[tid]  = (e < 0) ? -1 : sv;
        frac_s[tid][0] = frac_diff[(size_t)ec * 3 + 0];
        frac_s[tid][1] = frac_diff[(size_t)ec * 3 + 1];
        frac_s[tid][2] = frac_diff[(size_t)ec * 3 + 2];
    }
    __syncthreads();   // B1: indices + frac ready

    // Stage one pass: 384 units (row 32, z 3, q2 4), <=2 per thread.
    auto stage_pass = [&](int p) {
#pragma unroll
        for (int uu = 0; uu < 2; ++uu) {
            int u = tid + uu * 256;
            if (u < 384) {
                int row = u & 31;
                int zz = u >> 5;           // 0..11 = z*4 + q2
                int z = zz >> 2, q2 = zz & 3;
                int kg = p * 3 + z;
                int d = kg >> 1, fb = kg & 1;
                float x = frac_s[row][d];
                float c1 = __builtin_amdgcn_cosf(x);
                float s1 = __builtin_amdgcn_sinf(x);
                float t0 = x * (float)(fb * 32 + q2 * 8);
                float rev = t0 - floorf(t0);
                float s = __builtin_amdgcn_sinf(rev);
                float c = __builtin_amdgcn_cosf(rev);
                f16 avs[8], avc[8];
#pragma unroll
                for (int j = 0; j < 8; ++j) {
                    avs[j] = (f16)s; avc[j] = (f16)c;
                    float ns = s * c1 + c * s1;
                    float nc = c * c1 - s * s1;
                    s = ns; c = nc;
                }
                int mb = row >> 4;
                int lslot = (row & 15) + 16 * q2;
                *(half8*)(bufB + (((z    ) * 2 + mb) * 64 + lslot) * 8) = *(half8*)avs;
                *(half8*)(bufB + (((z + 3) * 2 + mb) * 64 + lslot) * 8) = *(half8*)avc;
            }
        }
    };

    // ---- R-fill: thread owns row m = tid>>3; chunks cc = (tid&7) + 8*i.
    {
        int m = tid >> 3, c0 = tid & 7;
        const f16* pa = Hh1    + (size_t)src_s[m] * 256 + c0 * 8;
        const f16* pb = Hh2    + (size_t)dst_s[m] * 256 + c0 * 8;
        const f16* pc = latW16 + (size_t)g_s[m]   * 256 + c0 * 8;
        f16* pd = bufA + m * 264 + c0 * 8;
#pragma unroll
        for (int i = 0; i < 4; ++i) {
            half8 a = *(const half8*)(pa + i * 64);
            half8 b = *(const half8*)(pb + i * 64);
            half8 c = *(const half8*)(pc + i * 64);
            *(half8*)(pd + i * 64) = a + b + c;
        }
    }
    stage_pass(0);
    __syncthreads();   // B2: R tile + pass-0 frags ready

    int lane = tid & 63, w = tid >> 6;
    int l15 = lane & 15, q = lane >> 4;

    // ---- swapped GEMM1: e1^T[Hcol][edge] = Wfd^T @ fd^T + R^T.
    f32x4 acc[4][2];
#pragma unroll
    for (int mi = 0; mi < 4; ++mi)
#pragma unroll
        for (int g = 0; g < 2; ++g) {
            int edge = g * 16 + l15;
            int hc0 = (w*4 + mi) * 16 + q * 4;
            half4 rv = *(const half4*)(bufA + edge * 264 + hc0);
            f32x4 a;
            a[0] = (float)rv[0]; a[1] = (float)rv[1];
            a[2] = (float)rv[2]; a[3] = (float)rv[3];
            acc[mi][g] = a;
        }

#pragma unroll
    for (int p = 0; p < 2; ++p) {
        if (p == 1) {
            __syncthreads();   // B2b: pass-0 frag reads done
            stage_pass(1);
            __syncthreads();   // B2c: pass-1 frags ready
        }
#pragma unroll
        for (int z = 0; z < 3; ++z) {
            int kg = p * 3 + z;
            half8 aS[4], aC[4];
#pragma unroll
            for (int mi = 0; mi < 4; ++mi) {
                int mblk = w * 4 + mi;
                aS[mi] = *(const half8*)(Wfd + ((size_t)(mblk*12 + kg)     * 64 + lane) * 8);
                aC[mi] = *(const half8*)(Wfd + ((size_t)(mblk*12 + kg + 6) * 64 + lane) * 8);
            }
#pragma unroll
            for (int g = 0; g < 2; ++g) {
                half8 bS = *(const half8*)(bufB + (((z    ) * 2 + g) * 64 + lane) * 8);
                half8 bC = *(const half8*)(bufB + (((z + 3) * 2 + g) * 64 + lane) * 8);
#pragma unroll
                for (int mi = 0; mi < 4; ++mi) {
                    acc[mi][g] = __builtin_amdgcn_mfma_f32_16x16x32_f16(aS[mi], bS, acc[mi][g], 0, 0, 0);
                    acc[mi][g] = __builtin_amdgcn_mfma_f32_16x16x32_f16(aC[mi], bC, acc[mi][g], 0, 0, 0);
                }
            }
        }
    }

    // ---- epilogue 1: silu -> e1 row-major [edge][264] (owner-exclusive)
#pragma unroll
    for (int mi = 0; mi < 4; ++mi)
#pragma unroll
        for (int g = 0; g < 2; ++g) {
            int edge = g * 16 + l15;
            int hc0 = (w*4 + mi) * 16 + q * 4;
            half4 tv;
            tv[0] = (f16)fast_silu(acc[mi][g][0]);
            tv[1] = (f16)fast_silu(acc[mi][g][1]);
            tv[2] = (f16)fast_silu(acc[mi][g][2]);
            tv[3] = (f16)fast_silu(acc[mi][g][3]);
            *(half4*)(bufA + edge * 264 + hc0) = tv;
        }
    __syncthreads();   // B3: e1 tile ready (also: all pass-1 frag reads done)

    // ---- swapped GEMM2: e2^T = We2^T @ e1^T
    f32x4 acc2[4][2];
    const f32x4 z4 = {0.f, 0.f, 0.f, 0.f};
#pragma unroll
    for (int a = 0; a < 4; ++a)
#pragma unroll
        for (int b = 0; b < 2; ++b) acc2[a][b] = z4;
#pragma unroll
    for (int ks = 0; ks < 8; ++ks) {
        half8 bfr[2];
#pragma unroll
        for (int g = 0; g < 2; ++g)
            bfr[g] = *(const half8*)(bufA + (g*16 + l15) * 264 + ks*32 + q*8);
#pragma unroll
        for (int mi = 0; mi < 4; ++mi) {
            half8 afr = *(const half8*)(We2 + ((size_t)((w*4 + mi)*8 + ks) * 64 + lane) * 8);
#pragma unroll
            for (int g = 0; g < 2; ++g)
                acc2[mi][g] = __builtin_amdgcn_mfma_f32_16x16x32_f16(afr, bfr[g], acc2[mi][g], 0, 0, 0);
        }
    }

    // ---- epilogue 2: silu(+eb2) -> e2 tile [Hcol][edge pad36] f16 in bufB
    // (frags dead since GEMM1; B3 covers the WAR). Invalid edges -> 0.
    {
        float msk[2];
#pragma unroll
        for (int g = 0; g < 2; ++g)
            msk[g] = (srcr[g*16 + l15] >= 0) ? 1.f : 0.f;
#pragma unroll
        for (int mi = 0; mi < 4; ++mi) {
            int hc0 = (w*4 + mi) * 16 + q * 4;
            float4 e4 = *(const float4*)(eb2 + hc0);
#pragma unroll
            for (int g = 0; g < 2; ++g) {
                int edge = g * 16 + l15;
                bufB[(hc0 + 0) * 36 + edge] = (f16)(fast_silu(acc2[mi][g][0] + e4.x) * msk[g]);
                bufB[(hc0 + 1) * 36 + edge] = (f16)(fast_silu(acc2[mi][g][1] + e4.y) * msk[g]);
                bufB[(hc0 + 2) * 36 + edge] = (f16)(fast_silu(acc2[mi][g][2] + e4.z) * msk[g]);
                bufB[(hc0 + 3) * 36 + edge] = (f16)(fast_silu(acc2[mi][g][3] + e4.w) * msk[g]);
            }
        }
    }
    __syncthreads();   // B4: e2 tile ready

    // ---- segmented reduction: thread t owns Hcol t; edges contiguous -> b64.
    {
        int t = tid;
        float run = 0.f;
        int cur = srcr[0];
#pragma unroll
        for (int m4 = 0; m4 < 8; ++m4) {
            half4 vv = *(const half4*)(bufB + t * 36 + m4 * 4);
#pragma unroll
            for (int jj = 0; jj < 4; ++jj) {
                int mm = m4 * 4 + jj;
                int s = srcr[mm];
                float v = (float)vv[jj];
                if (s != cur) {
                    if (cur >= 0) atomicAdd(aggsum + (size_t)cur * 256 + t, run);
                    cur = s; run = v;
                } else run += v;
            }
        }
        if (cur >= 0) atomicAdd(aggsum + (size_t)cur * 256 + t, run);
    }
}

// ---------------------------------------------------------------------------
// Node post (operand-swapped): agg = aggsum/max(cnt,1);
// t = silu(Nh + agg@Wn1a + nb1); out = h + silu(t@Wn2 + nb2).
// Load phase: linear lane-major mapping -> 1 KB contiguous per instruction.
// ---------------------------------------------------------------------------
__global__ __launch_bounds__(256) void node_post_kernel(
    const float* __restrict__ aggsum, const int* __restrict__ cnt,
    const f16* __restrict__ Nh, const f16* __restrict__ Wn1a, const f16* __restrict__ Wn2,
    const float* __restrict__ nb1, const float* __restrict__ nb2,
    const float* __restrict__ h, float* __restrict__ out)
{
    __shared__ f16 T[64 * 264];
    int tid = threadIdx.x;
    int lane = tid & 63, w = tid >> 6;
    {
#pragma unroll
        for (int i = 0; i < 16; ++i) {
            int rl = w + 4 * i;                 // local row 0..63, wave-uniform
            int row = blockIdx.x * 64 + rl;
            int rowc = min(row, N_NODES - 1);
            float inv = 1.f / fmaxf((float)cnt[rowc], 1.f);
            float4 x = ((const float4*)(aggsum + (size_t)rowc * 256))[lane];
            half4 av;
            av[0] = (f16)(x.x * inv);
            av[1] = (f16)(x.y * inv);
            av[2] = (f16)(x.z * inv);
            av[3] = (f16)(x.w * inv);
            *(half4*)(T + rl * 264 + lane * 4) = av;
        }
    }
    __syncthreads();

    int l15 = lane & 15, q = lane >> 4;
    const f32x4 z4 = {0.f, 0.f, 0.f, 0.f};

    // GEMM1 swapped: acc[mi][g], A = Wn1a frag, B = T rows (agg)
    f32x4 acc[4][4];
#pragma unroll
    for (int a = 0; a < 4; ++a)
#pragma unroll
        for (int b = 0; b < 4; ++b) acc[a][b] = z4;
    for (int ks = 0; ks < 8; ++ks) {
        half8 bfr[4];
#pragma unroll
        for (int g = 0; g < 4; ++g)
            bfr[g] = *(const half8*)(T + (g*16 + l15) * 264 + ks*32 + q*8);
#pragma unroll
        for (int mi = 0; mi < 4; ++mi) {
            half8 afr = *(const half8*)(Wn1a + ((size_t)((w*4 + mi)*8 + ks) * 64 + lane) * 8);
#pragma unroll
            for (int g = 0; g < 4; ++g)
                acc[mi][g] = __builtin_amdgcn_mfma_f32_16x16x32_f16(afr, bfr[g], acc[mi][g], 0, 0, 0);
        }
    }
    __syncthreads();   // all T reads done

    // t = silu(acc + Nh + nb1) -> T'[node][hc0..3] half4 writes
#pragma unroll
    for (int mi = 0; mi < 4; ++mi) {
        int hc0 = (w*4 + mi) * 16 + q * 4;
        f32x4 b1v = *(const f32x4*)(nb1 + hc0);
#pragma unroll
        for (int g = 0; g < 4; ++g) {
            int nodeg = blockIdx.x * 64 + g*16 + l15;
            int orc = min(nodeg, N_NODES - 1);
            half4 nh4 = *(const half4*)(Nh + (size_t)orc * 256 + hc0);
            half4 tv;
            tv[0] = (f16)fast_silu(acc[mi][g][0] + (float)nh4[0] + b1v[0]);
            tv[1] = (f16)fast_silu(acc[mi][g][1] + (float)nh4[1] + b1v[1]);
            tv[2] = (f16)fast_silu(acc[mi][g][2] + (float)nh4[2] + b1v[2]);
            tv[3] = (f16)fast_silu(acc[mi][g][3] + (float)nh4[3] + b1v[3]);
            *(half4*)(T + (g*16 + l15) * 264 + hc0) = tv;
        }
    }
    __syncthreads();

    // GEMM2 swapped: A = Wn2 frag, B = T' rows
    f32x4 acc2[4][4];
#pragma unroll
    for (int a = 0; a < 4; ++a)
#pragma unroll
        for (int b = 0; b < 4; ++b) acc2[a][b] = z4;
    for (int ks = 0; ks < 8; ++ks) {
        half8 bfr[4];
#pragma unroll
        for (int g = 0; g < 4; ++g)
            bfr[g] = *(const half8*)(T + (g*16 + l15) * 264 + ks*32 + q*8);
#pragma unroll
        for (int mi = 0; mi < 4; ++mi) {
            half8 afr = *(const half8*)(Wn2 + ((size_t)((w*4 + mi)*8 + ks) * 64 + lane) * 8);
#pragma unroll
            for (int g = 0; g < 4; ++g)
                acc2[mi][g] = __builtin_amdgcn_mfma_f32_16x16x32_f16(afr, bfr[g], acc2[mi][g], 0, 0, 0);
        }
    }

    // out = h + silu(acc2 + nb2) -> float4 stores
#pragma unroll
    for (int g = 0; g < 4; ++g) {
        int orow = blockIdx.x * 64 + g*16 + l15;
        if (orow < N_NODES) {
#pragma unroll
            for (int mi = 0; mi < 4; ++mi) {
                int hc0 = (w*4 + mi) * 16 + q * 4;
                f32x4 b2v = *(const f32x4*)(nb2 + hc0);
                f32x4 hv  = *(const f32x4*)(h + (size_t)orow * 256 + hc0);
                f32x4 ov;
                ov[0] = hv[0] + fast_silu(acc2[mi][g][0] + b2v[0]);
                ov[1] = hv[1] + fast_silu(acc2[mi][g][1] + b2v[1]);
                ov[2] = hv[2] + fast_silu(acc2[mi][g][2] + b2v[2]);
                ov[3] = hv[3] + fast_silu(acc2[mi][g][3] + b2v[3]);
                *(f32x4*)(out + (size_t)orow * 256 + hc0) = ov;
            }
        }
    }
}

// ---------------------------------------------------------------------------
extern "C" void kernel_launch(void* const* d_in, const int* in_sizes, int n_in,
                              void* d_out, int out_size, void* d_ws, size_t ws_size,
                              hipStream_t stream) {
    const float* h          = (const float*)d_in[0];
    const float* lattices   = (const float*)d_in[2];
    const int*   edge_index = (const int*)d_in[3];
    const int*   edge2graph = (const int*)d_in[4];
    const float* frac_diff  = (const float*)d_in[5];
    const float* ln_gamma   = (const float*)d_in[6];
    const float* ln_beta    = (const float*)d_in[7];
    const float* eW1        = (const float*)d_in[8];
    const float* eb1        = (const float*)d_in[9];
    const float* eW2        = (const float*)d_in[10];
    const float* eb2        = (const float*)d_in[11];
    const float* nW1        = (const float*)d_in[12];
    const float* nb1        = (const float*)d_in[13];
    const float* nW2        = (const float*)d_in[14];
    const float* nb2        = (const float*)d_in[15];
    float* out = (float*)d_out;
    char* base = (char*)d_ws;

    // workspace layout (byte offsets)
    float* aggsum   = (float*)(base + 0);              // 51,200,000 B
    int*   cnt      = (int*)  (base + 51200000);       // 200,704
    int*   off      = (int*)  (base + 51400704);       // 200,704
    int*   tmp      = (int*)  (base + 51601408);       // 200,704 (slots 50000+ reused as scan scratch)
    int*   sorted_e = (int*)  (base + 51802112);       // 2,000,000
    f16*   latW16   = (f16*)  (base + 53802112);       // 65,536
    f16*   Hh1      = (f16*)  (base + 53867648);       // 25,600,000
    f16*   Hh2      = (f16*)  (base + 79467648);
    f16*   Nh       = (f16*)  (base + 105067648);
    f16*   packs    = (f16*)  (base + 130667648);
    f16* Wfd  = packs;            // 98,304 halfs (K=384)
    f16* Whi  = Wfd  + 98304;
    f16* Whj  = Whi  + 65536;
    f16* We2  = Whj  + 65536;
    f16* Wn1h = We2  + 65536;
    f16* Wn1a = Wn1h + 65536;
    f16* Wn2  = Wn1a + 65536;     // ends at byte 131,650,688
    if (ws_size < (size_t)131650688) return;

    int* partials = tmp + 50000;  // 49 ints (unused tail of tmp)
    int* blkbase  = tmp + 50080;  // 49 ints

    // zero aggsum + cnt + off + tmp
    hipMemsetAsync(base, 0, (size_t)51802112, stream);

    // fused: 7 weight packs + latW + histogram
    prep_fused<<<2322, 256, 0, stream>>>(
        eW1, eW2, nW1, nW2, Wfd, Whi, Whj, We2, Wn1h, Wn1a, Wn2,
        lattices, eb1, latW16, edge_index, cnt);

    scan_part<<<49, 1024, 0, stream>>>(cnt, off, partials);
    scan_tops<<<1, 64, 0, stream>>>(partials, blkbase);

    // fused: CSR position-scatter + LayerNorm/3-GEMM (independent work)
    pos_ln_kernel<<<POS_BLOCKS + LN_BLOCKS, 256, 0, stream>>>(
        edge_index, off, blkbase, tmp, sorted_e,
        h, ln_gamma, ln_beta, Whi, Whj, Wn1h, Hh1, Hh2, Nh);

    edge_kernel<<<(E_EDGES + 31) / 32, 256, 0, stream>>>(
        sorted_e, edge_index, edge2graph, frac_diff, Hh1, Hh2, latW16, Wfd, We2, eb2, aggsum);

    node_post_kernel<<<(N_NODES + 63) / 64, 256, 0, stream>>>(
        aggsum, cnt, Nh, Wn1a, Wn2, nb1, nb2, h, out);
}

// Round 11
// 577.369 us; speedup vs baseline: 1.0622x; 1.0231x over previous
//
#include <hip/hip_runtime.h>
#include <hip/hip_bf16.h>
#include <math.h>

// Problem constants
#define N_NODES 50000
#define E_EDGES 500000
#define G_GRAPHS 128
#define N_PAD 50176   // 196*256 = 49*1024, padded node count for scan
#define POS_BLOCKS 1954   // ceil(E/256)
#define LN_BLOCKS 782     // ceil(N/64)
// H = 256, NF = 64, EDGE_IN = 905 (rows: hi 0..255 | hj 256..511 | lat 512..520 | fd 521..904)

typedef _Float16 f16;
typedef _Float16 half8 __attribute__((ext_vector_type(8)));
typedef _Float16 half4 __attribute__((ext_vector_type(4)));
typedef float f32x4 __attribute__((ext_vector_type(4)));

// silu via v_rcp: avoids the precise-divide expansion (~9 instrs) of 1.0f/x
__device__ __forceinline__ float fast_silu(float x) {
    return x * __builtin_amdgcn_rcpf(1.0f + __expf(-x));
}

// ---------------------------------------------------------------------------
// Pack helper (device): [K x 256] row-major fp32 -> MFMA fragment-linear f16.
// chunk (nb, kstep): lane holds W[k=kstep*32+(lane>>4)*8+j][n=nb*16+(lane&15)].
// Serves BOTH as B-fragment (k,n) and as A-fragment (n,k) of W^T for the
// operand-swapped GEMMs.
// ---------------------------------------------------------------------------
__device__ __forceinline__ void pack_dev(const float* __restrict__ src,
                                         f16* __restrict__ dst, int Ksteps, int ltid) {
    int lane = ltid & 63;
    int chunk = ltid >> 6;
    int kstep = chunk % Ksteps;
    int nb = chunk / Ksteps;
    if (nb >= 16) return;
    int n = nb * 16 + (lane & 15);
    int k0 = kstep * 32 + (lane >> 4) * 8;
    f16* d = dst + (size_t)ltid * 8;
#pragma unroll
    for (int j = 0; j < 8; ++j)
        d[j] = (f16)src[(size_t)(k0 + j) * 256 + n];
}

// ---------------------------------------------------------------------------
// Fused prep: 7 weight packs + latW + edge histogram in ONE launch.
// ---------------------------------------------------------------------------
__global__ __launch_bounds__(256) void prep_fused(
    const float* __restrict__ eW1, const float* __restrict__ eW2,
    const float* __restrict__ nW1, const float* __restrict__ nW2,
    f16* __restrict__ Wfd, f16* __restrict__ Whi, f16* __restrict__ Whj,
    f16* __restrict__ We2, f16* __restrict__ Wn1h, f16* __restrict__ Wn1a,
    f16* __restrict__ Wn2,
    const float* __restrict__ lat, const float* __restrict__ eb1,
    f16* __restrict__ latW16,
    const int* __restrict__ ei, int* __restrict__ cnt)
{
    int b = blockIdx.x, t = threadIdx.x;
    if (b < 48)        { pack_dev(eW1 + 521 * 256, Wfd,  12, b * 256 + t); }
    else if (b < 80)   { pack_dev(eW1,             Whi,  8, (b - 48) * 256 + t); }
    else if (b < 112)  { pack_dev(eW1 + 256 * 256, Whj,  8, (b - 80) * 256 + t); }
    else if (b < 144)  { pack_dev(eW2,             We2,  8, (b - 112) * 256 + t); }
    else if (b < 176)  { pack_dev(nW1,             Wn1h, 8, (b - 144) * 256 + t); }
    else if (b < 208)  { pack_dev(nW1 + 256 * 256, Wn1a, 8, (b - 176) * 256 + t); }
    else if (b < 240)  { pack_dev(nW2,             Wn2,  8, (b - 208) * 256 + t); }
    else if (b < 368) {
        int g = b - 240, n = t;
        float l[9];
#pragma unroll
        for (int i = 0; i < 9; ++i) l[i] = lat[g * 9 + i];
        float acc = eb1[n];
#pragma unroll
        for (int i = 0; i < 3; ++i)
#pragma unroll
            for (int j = 0; j < 3; ++j) {
                float ip = l[i*3+0]*l[j*3+0] + l[i*3+1]*l[j*3+1] + l[i*3+2]*l[j*3+2];
                acc += ip * eW1[(size_t)(512 + i*3 + j) * 256 + n];
            }
        latW16[g * 256 + n] = (f16)acc;
    } else {
        int e = (b - 368) * 256 + t;
        if (e < E_EDGES) atomicAdd(cnt + ei[e], 1);
    }
}

// ---------------------------------------------------------------------------
// Parallel CSR scan: per-block exclusive scan + block totals, then a single
// wave scans the 49 totals. pos adds base[s>>10].
// ---------------------------------------------------------------------------
__global__ __launch_bounds__(1024) void scan_part(const int* __restrict__ cnt,
                                                  int* __restrict__ off,
                                                  int* __restrict__ partials) {
    __shared__ int wsum[16], wpre[16];
    int t = threadIdx.x, lane = t & 63, w = t >> 6;
    int c = blockIdx.x * 1024 + t;
    int v = cnt[c];
    int x = v;
#pragma unroll
    for (int d = 1; d < 64; d <<= 1) { int nn = __shfl_up(x, d); if (lane >= d) x += nn; }
    if (lane == 63) wsum[w] = x;
    __syncthreads();
    if (t < 16) {
        int s = wsum[t];
        int y = s;
#pragma unroll
        for (int d = 1; d < 16; d <<= 1) { int nn = __shfl_up(y, d, 16); if (t >= d) y += nn; }
        wpre[t] = y - s;
        if (t == 15) partials[blockIdx.x] = y;
    }
    __syncthreads();
    off[c] = wpre[w] + x - v;   // block-local exclusive
}

__global__ void scan_tops(const int* __restrict__ partials, int* __restrict__ base) {
    int t = threadIdx.x;   // 64 threads, 49 used
    int v = (t < 49) ? partials[t] : 0;
    int x = v;
#pragma unroll
    for (int d = 1; d < 64; d <<= 1) { int nn = __shfl_up(x, d); if (t >= d) x += nn; }
    if (t < 49) base[t] = x - v;   // exclusive
}

// ---------------------------------------------------------------------------
// FUSED pos + ln_gemm (unchanged from R10): scatter overlaps GEMM compute.
// ---------------------------------------------------------------------------
__global__ __launch_bounds__(256) void pos_ln_kernel(
    const int* __restrict__ ei, const int* __restrict__ off,
    const int* __restrict__ base, int* __restrict__ tmp,
    int* __restrict__ sorted_e,
    const float* __restrict__ h, const float* __restrict__ gamma, const float* __restrict__ beta,
    const f16* __restrict__ Whi, const f16* __restrict__ Whj, const f16* __restrict__ Wn1,
    f16* __restrict__ Hh1, f16* __restrict__ Hh2, f16* __restrict__ Nh)
{
    __shared__ f16 Aln[64 * 264];
    int tid = threadIdx.x;

    if (blockIdx.x < POS_BLOCKS) {
        int e = blockIdx.x * 256 + tid;
        if (e < E_EDGES) {
            int s = ei[e];
            int p = off[s] + base[s >> 10] + atomicAdd(tmp + s, 1);
            sorted_e[p] = e;
        }
        return;
    }
    int lb = blockIdx.x - POS_BLOCKS;

    // ---- LayerNorm load phase: 16-lanes-per-row mapping, contiguous loads.
    int l15g = tid & 15;          // col-group lane
    int rq   = tid >> 4;          // 0..15: row slot within a round

    float4 gv[4], bv[4];
#pragma unroll
    for (int i = 0; i < 4; ++i) {
        gv[i] = ((const float4*)gamma)[l15g + 16*i];
        bv[i] = ((const float4*)beta )[l15g + 16*i];
    }

#pragma unroll
    for (int r4 = 0; r4 < 4; ++r4) {
        int rl = r4 * 16 + rq;                 // local row 0..63
        int row = lb * 64 + rl;
        int rowc = min(row, N_NODES - 1);
        const float4* hp4 = (const float4*)(h + (size_t)rowc * 256);
        float4 xv[4];
        float s = 0.f, ss = 0.f;
#pragma unroll
        for (int i = 0; i < 4; ++i) {
            float4 x = hp4[l15g + 16*i];
            xv[i] = x;
            s  += x.x + x.y + x.z + x.w;
            ss += x.x*x.x + x.y*x.y + x.z*x.z + x.w*x.w;
        }
#pragma unroll
        for (int m = 1; m < 16; m <<= 1) {
            s  += __shfl_xor(s,  m);
            ss += __shfl_xor(ss, m);
        }
        float mean = s * (1.f / 256.f);
        float var  = ss * (1.f / 256.f) - mean * mean;
        float rstd = rsqrtf(var + 1e-5f);
#pragma unroll
        for (int i = 0; i < 4; ++i) {
            half4 o;
            o[0] = (f16)((xv[i].x - mean) * rstd * gv[i].x + bv[i].x);
            o[1] = (f16)((xv[i].y - mean) * rstd * gv[i].y + bv[i].y);
            o[2] = (f16)((xv[i].z - mean) * rstd * gv[i].z + bv[i].z);
            o[3] = (f16)((xv[i].w - mean) * rstd * gv[i].w + bv[i].w);
            *(half4*)(Aln + rl * 264 + (l15g + 16*i) * 4) = o;
        }
    }
    __syncthreads();

    int lane = tid & 63, w = tid >> 6;
    int l15 = lane & 15, q = lane >> 4;
    const f16* Ws[3] = {Whi, Whj, Wn1};
    f16* Os[3] = {Hh1, Hh2, Nh};
    const f32x4 z4 = {0.f, 0.f, 0.f, 0.f};

    for (int widx = 0; widx < 3; ++widx) {
        f32x4 acc[4][4];   // [mi Hcol-block][g node-group]
#pragma unroll
        for (int a = 0; a < 4; ++a)
#pragma unroll
            for (int b = 0; b < 4; ++b) acc[a][b] = z4;
        const f16* W = Ws[widx];
        for (int ks = 0; ks < 8; ++ks) {
            half8 bfr[4];
#pragma unroll
            for (int g = 0; g < 4; ++g)
                bfr[g] = *(const half8*)(Aln + (g*16 + l15) * 264 + ks*32 + q*8);
#pragma unroll
            for (int mi = 0; mi < 4; ++mi) {
                half8 afr = *(const half8*)(W + ((size_t)((w*4 + mi)*8 + ks) * 64 + lane) * 8);
#pragma unroll
                for (int g = 0; g < 4; ++g)
                    acc[mi][g] = __builtin_amdgcn_mfma_f32_16x16x32_f16(afr, bfr[g], acc[mi][g], 0, 0, 0);
            }
        }
        f16* O = Os[widx];
#pragma unroll
        for (int g = 0; g < 4; ++g) {
            int orow = lb * 64 + g*16 + l15;
            if (orow < N_NODES) {
#pragma unroll
                for (int mi = 0; mi < 4; ++mi) {
                    int hc0 = (w*4 + mi) * 16 + q * 4;
                    half4 hv;
                    hv[0] = (f16)acc[mi][g][0]; hv[1] = (f16)acc[mi][g][1];
                    hv[2] = (f16)acc[mi][g][2]; hv[3] = (f16)acc[mi][g][3];
                    *(half4*)(O + (size_t)orow * 256 + hc0) = hv;
                }
            }
        }
    }
}

// ---------------------------------------------------------------------------
// Edge kernel v16: M=64 tile, 512 threads (8 waves). Each 32-edge v11 block
// read the FULL packed Wfd+We2 (320 KB) from L2 -> 10 KB/edge -> ~5 GB of
// L2->L1 weight traffic (~145 us at the 34.5 TB/s L2 ceiling). Doubling the
// tile amortizes the same 320 KB over 64 edges (5 KB/edge) and halves
// per-edge barrier count. Wave w owns Hcol-blocks {2w,2w+1} x 4 edge-groups
// (acc[2][4]); per-thread MFMA count unchanged. LDS 70.7 KB -> 2 blocks/CU
// = 16 waves/CU, SAME wave count and per-CU gather footprint as v11 (R7's
// occupancy->L2-footprint regression cannot trigger). Segred: 2 threads per
// Hcol, 32 rows each (boundary split safe under atomics).
// ---------------------------------------------------------------------------
__global__ __launch_bounds__(512, 4) void edge_kernel(
    const int* __restrict__ sorted_e,
    const int* __restrict__ edge_index, const int* __restrict__ edge2graph,
    const float* __restrict__ frac_diff,
    const f16* __restrict__ Hh1, const f16* __restrict__ Hh2, const f16* __restrict__ latW16,
    const f16* __restrict__ Wfd, const f16* __restrict__ We2, const float* __restrict__ eb2,
    float* __restrict__ aggsum)
{
    __shared__ f16 bufA[64 * 264];   // 33.8 KB: R tile -> e1 tile, row-major [edge][264]
    __shared__ f16 bufB[17408];      // 34.8 KB: frag window (24.6) / e2 tile [256][68]
    __shared__ float frac_s[64][4];
    __shared__ int src_s[64], dst_s[64], g_s[64], srcr[64];
    int tid = threadIdx.x;
    int e0 = blockIdx.x * 64;

    if (tid < 64) {
        int slot = e0 + tid;
        int e = (slot < E_EDGES) ? sorted_e[slot] : -1;
        int ec = e < 0 ? 0 : e;
        int sv = edge_index[ec];
        src_s[tid] = sv;
        dst_s[tid] = edge_index[E_EDGES + ec];
        g_s[tid]   = edge2graph[ec];
        srcr[tid]  = (e < 0) ? -1 : sv;
        frac_s[tid][0] = frac_diff[(size_t)ec * 3 + 0];
        frac_s[tid][1] = frac_diff[(size_t)ec * 3 + 1];
        frac_s[tid][2] = frac_diff[(size_t)ec * 3 + 2];
    }
    __syncthreads();   // B1: indices + frac ready

    // Stage one pass: 768 units (row 64, z 3, q2 4), <=2 per thread.
    // Unit writes sin frag slot z (edge-group mb), cos at z+3, lane
    // (row&15)+16*q2, covering k = kg*32 + q2*8 + j via 8 rotation steps
    // from a direct-trig seed.
    auto stage_pass = [&](int p) {
#pragma unroll
        for (int uu = 0; uu < 2; ++uu) {
            int u = tid + uu * 512;
            if (u < 768) {
                int row = u & 63;
                int zz = u >> 6;           // 0..11 = z*4 + q2
                int z = zz >> 2, q2 = zz & 3;
                int kg = p * 3 + z;
                int d = kg >> 1, fb = kg & 1;
                float x = frac_s[row][d];
                float c1 = __builtin_amdgcn_cosf(x);
                float s1 = __builtin_amdgcn_sinf(x);
                float t0 = x * (float)(fb * 32 + q2 * 8);
                float rev = t0 - floorf(t0);
                float s = __builtin_amdgcn_sinf(rev);
                float c = __builtin_amdgcn_cosf(rev);
                f16 avs[8], avc[8];
#pragma unroll
                for (int j = 0; j < 8; ++j) {
                    avs[j] = (f16)s; avc[j] = (f16)c;
                    float ns = s * c1 + c * s1;
                    float nc = c * c1 - s * s1;
                    s = ns; c = nc;
                }
                int mb = row >> 4;                  // edge-group 0..3
                int lslot = (row & 15) + 16 * q2;
                *(half8*)(bufB + (((z    ) * 4 + mb) * 64 + lslot) * 8) = *(half8*)avs;
                *(half8*)(bufB + (((z + 3) * 4 + mb) * 64 + lslot) * 8) = *(half8*)avc;
            }
        }
    };

    // ---- R-fill: thread owns row m = tid>>3 (0..63); chunks (tid&7) + 8*i.
    {
        int m = tid >> 3, c0 = tid & 7;
        const f16* pa = Hh1    + (size_t)src_s[m] * 256 + c0 * 8;
        const f16* pb = Hh2    + (size_t)dst_s[m] * 256 + c0 * 8;
        const f16* pc = latW16 + (size_t)g_s[m]   * 256 + c0 * 8;
        f16* pd = bufA + m * 264 + c0 * 8;
#pragma unroll
        for (int i = 0; i < 4; ++i) {
            half8 a = *(const half8*)(pa + i * 64);
            half8 b = *(const half8*)(pb + i * 64);
            half8 c = *(const half8*)(pc + i * 64);
            *(half8*)(pd + i * 64) = a + b + c;
        }
    }
    stage_pass(0);
    __syncthreads();   // B2: R tile + pass-0 frags ready

    int lane = tid & 63, w = tid >> 6;   // w 0..7
    int l15 = lane & 15, q = lane >> 4;

    // ---- swapped GEMM1: e1^T[Hcol][edge] = Wfd^T @ fd^T + R^T.
    // acc[mi][g]: Hcol = (w*2+mi)*16 + q*4 + rr, edge = g*16 + l15.
    f32x4 acc[2][4];
#pragma unroll
    for (int mi = 0; mi < 2; ++mi)
#pragma unroll
        for (int g = 0; g < 4; ++g) {
            int edge = g * 16 + l15;
            int hc0 = (w*2 + mi) * 16 + q * 4;
            half4 rv = *(const half4*)(bufA + edge * 264 + hc0);
            f32x4 a;
            a[0] = (float)rv[0]; a[1] = (float)rv[1];
            a[2] = (float)rv[2]; a[3] = (float)rv[3];
            acc[mi][g] = a;
        }

#pragma unroll
    for (int p = 0; p < 2; ++p) {
        if (p == 1) {
            __syncthreads();   // B2b: pass-0 frag reads done
            stage_pass(1);
            __syncthreads();   // B2c: pass-1 frags ready
        }
#pragma unroll
        for (int z = 0; z < 3; ++z) {
            int kg = p * 3 + z;
            half8 aS[2], aC[2];
#pragma unroll
            for (int mi = 0; mi < 2; ++mi) {
                int mblk = w * 2 + mi;
                aS[mi] = *(const half8*)(Wfd + ((size_t)(mblk*12 + kg)     * 64 + lane) * 8);
                aC[mi] = *(const half8*)(Wfd + ((size_t)(mblk*12 + kg + 6) * 64 + lane) * 8);
            }
#pragma unroll
            for (int g = 0; g < 4; ++g) {
                half8 bS = *(const half8*)(bufB + (((z    ) * 4 + g) * 64 + lane) * 8);
                half8 bC = *(const half8*)(bufB + (((z + 3) * 4 + g) * 64 + lane) * 8);
#pragma unroll
                for (int mi = 0; mi < 2; ++mi) {
                    acc[mi][g] = __builtin_amdgcn_mfma_f32_16x16x32_f16(aS[mi], bS, acc[mi][g], 0, 0, 0);
                    acc[mi][g] = __builtin_amdgcn_mfma_f32_16x16x32_f16(aC[mi], bC, acc[mi][g], 0, 0, 0);
                }
            }
        }
    }

    // ---- epilogue 1: silu -> e1 row-major [edge][264] (owner-exclusive)
#pragma unroll
    for (int mi = 0; mi < 2; ++mi)
#pragma unroll
        for (int g = 0; g < 4; ++g) {
            int edge = g * 16 + l15;
            int hc0 = (w*2 + mi) * 16 + q * 4;
            half4 tv;
            tv[0] = (f16)fast_silu(acc[mi][g][0]);
            tv[1] = (f16)fast_silu(acc[mi][g][1]);
            tv[2] = (f16)fast_silu(acc[mi][g][2]);
            tv[3] = (f16)fast_silu(acc[mi][g][3]);
            *(half4*)(bufA + edge * 264 + hc0) = tv;
        }
    __syncthreads();   // B3: e1 tile ready (also: all pass-1 frag reads done)

    // ---- swapped GEMM2: e2^T = We2^T @ e1^T
    f32x4 acc2[2][4];
    const f32x4 z4 = {0.f, 0.f, 0.f, 0.f};
#pragma unroll
    for (int a = 0; a < 2; ++a)
#pragma unroll
        for (int b = 0; b < 4; ++b) acc2[a][b] = z4;
#pragma unroll
    for (int ks = 0; ks < 8; ++ks) {
        half8 bfr[4];
#pragma unroll
        for (int g = 0; g < 4; ++g)
            bfr[g] = *(const half8*)(bufA + (g*16 + l15) * 264 + ks*32 + q*8);
#pragma unroll
        for (int mi = 0; mi < 2; ++mi) {
            half8 afr = *(const half8*)(We2 + ((size_t)((w*2 + mi)*8 + ks) * 64 + lane) * 8);
#pragma unroll
            for (int g = 0; g < 4; ++g)
                acc2[mi][g] = __builtin_amdgcn_mfma_f32_16x16x32_f16(afr, bfr[g], acc2[mi][g], 0, 0, 0);
        }
    }

    // ---- epilogue 2: silu(+eb2) -> e2 tile [Hcol][edge pad68] f16 in bufB
    // (frags dead since GEMM1; B3 covers the WAR). Invalid edges -> 0.
    {
        float msk[4];
#pragma unroll
        for (int g = 0; g < 4; ++g)
            msk[g] = (srcr[g*16 + l15] >= 0) ? 1.f : 0.f;
#pragma unroll
        for (int mi = 0; mi < 2; ++mi) {
            int hc0 = (w*2 + mi) * 16 + q * 4;
            float4 e4 = *(const float4*)(eb2 + hc0);
#pragma unroll
            for (int g = 0; g < 4; ++g) {
                int edge = g * 16 + l15;
                bufB[(hc0 + 0) * 68 + edge] = (f16)(fast_silu(acc2[mi][g][0] + e4.x) * msk[g]);
                bufB[(hc0 + 1) * 68 + edge] = (f16)(fast_silu(acc2[mi][g][1] + e4.y) * msk[g]);
                bufB[(hc0 + 2) * 68 + edge] = (f16)(fast_silu(acc2[mi][g][2] + e4.z) * msk[g]);
                bufB[(hc0 + 3) * 68 + edge] = (f16)(fast_silu(acc2[mi][g][3] + e4.w) * msk[g]);
            }
        }
    }
    __syncthreads();   // B4: e2 tile ready

    // ---- segmented reduction: 2 threads per Hcol, 32 rows each (b64 reads).
    {
        int t = tid & 255, hf = tid >> 8;
        int r0 = hf * 32;
        float run = 0.f;
        int cur = srcr[r0];
#pragma unroll
        for (int m4 = 0; m4 < 8; ++m4) {
            half4 vv = *(const half4*)(bufB + t * 68 + r0 + m4 * 4);
#pragma unroll
            for (int jj = 0; jj < 4; ++jj) {
                int mm = r0 + m4 * 4 + jj;
                int s = srcr[mm];
                float v = (float)vv[jj];
                if (s != cur) {
                    if (cur >= 0) atomicAdd(aggsum + (size_t)cur * 256 + t, run);
                    cur = s; run = v;
                } else run += v;
            }
        }
        if (cur >= 0) atomicAdd(aggsum + (size_t)cur * 256 + t, run);
    }
}

// ---------------------------------------------------------------------------
// Node post (operand-swapped): agg = aggsum/max(cnt,1);
// t = silu(Nh + agg@Wn1a + nb1); out = h + silu(t@Wn2 + nb2).
// Load phase: linear lane-major mapping -> 1 KB contiguous per instruction.
// ---------------------------------------------------------------------------
__global__ __launch_bounds__(256) void node_post_kernel(
    const float* __restrict__ aggsum, const int* __restrict__ cnt,
    const f16* __restrict__ Nh, const f16* __restrict__ Wn1a, const f16* __restrict__ Wn2,
    const float* __restrict__ nb1, const float* __restrict__ nb2,
    const float* __restrict__ h, float* __restrict__ out)
{
    __shared__ f16 T[64 * 264];
    int tid = threadIdx.x;
    int lane = tid & 63, w = tid >> 6;
    {
#pragma unroll
        for (int i = 0; i < 16; ++i) {
            int rl = w + 4 * i;                 // local row 0..63, wave-uniform
            int row = blockIdx.x * 64 + rl;
            int rowc = min(row, N_NODES - 1);
            float inv = 1.f / fmaxf((float)cnt[rowc], 1.f);
            float4 x = ((const float4*)(aggsum + (size_t)rowc * 256))[lane];
            half4 av;
            av[0] = (f16)(x.x * inv);
            av[1] = (f16)(x.y * inv);
            av[2] = (f16)(x.z * inv);
            av[3] = (f16)(x.w * inv);
            *(half4*)(T + rl * 264 + lane * 4) = av;
        }
    }
    __syncthreads();

    int l15 = lane & 15, q = lane >> 4;
    const f32x4 z4 = {0.f, 0.f, 0.f, 0.f};

    // GEMM1 swapped: acc[mi][g], A = Wn1a frag, B = T rows (agg)
    f32x4 acc[4][4];
#pragma unroll
    for (int a = 0; a < 4; ++a)
#pragma unroll
        for (int b = 0; b < 4; ++b) acc[a][b] = z4;
    for (int ks = 0; ks < 8; ++ks) {
        half8 bfr[4];
#pragma unroll
        for (int g = 0; g < 4; ++g)
            bfr[g] = *(const half8*)(T + (g*16 + l15) * 264 + ks*32 + q*8);
#pragma unroll
        for (int mi = 0; mi < 4; ++mi) {
            half8 afr = *(const half8*)(Wn1a + ((size_t)((w*4 + mi)*8 + ks) * 64 + lane) * 8);
#pragma unroll
            for (int g = 0; g < 4; ++g)
                acc[mi][g] = __builtin_amdgcn_mfma_f32_16x16x32_f16(afr, bfr[g], acc[mi][g], 0, 0, 0);
        }
    }
    __syncthreads();   // all T reads done

    // t = silu(acc + Nh + nb1) -> T'[node][hc0..3] half4 writes
#pragma unroll
    for (int mi = 0; mi < 4; ++mi) {
        int hc0 = (w*4 + mi) * 16 + q * 4;
        f32x4 b1v = *(const f32x4*)(nb1 + hc0);
#pragma unroll
        for (int g = 0; g < 4; ++g) {
            int nodeg = blockIdx.x * 64 + g*16 + l15;
            int orc = min(nodeg, N_NODES - 1);
            half4 nh4 = *(const half4*)(Nh + (size_t)orc * 256 + hc0);
            half4 tv;
            tv[0] = (f16)fast_silu(acc[mi][g][0] + (float)nh4[0] + b1v[0]);
            tv[1] = (f16)fast_silu(acc[mi][g][1] + (float)nh4[1] + b1v[1]);
            tv[2] = (f16)fast_silu(acc[mi][g][2] + (float)nh4[2] + b1v[2]);
            tv[3] = (f16)fast_silu(acc[mi][g][3] + (float)nh4[3] + b1v[3]);
            *(half4*)(T + (g*16 + l15) * 264 + hc0) = tv;
        }
    }
    __syncthreads();

    // GEMM2 swapped: A = Wn2 frag, B = T' rows
    f32x4 acc2[4][4];
#pragma unroll
    for (int a = 0; a < 4; ++a)
#pragma unroll
        for (int b = 0; b < 4; ++b) acc2[a][b] = z4;
    for (int ks = 0; ks < 8; ++ks) {
        half8 bfr[4];
#pragma unroll
        for (int g = 0; g < 4; ++g)
            bfr[g] = *(const half8*)(T + (g*16 + l15) * 264 + ks*32 + q*8);
#pragma unroll
        for (int mi = 0; mi < 4; ++mi) {
            half8 afr = *(const half8*)(Wn2 + ((size_t)((w*4 + mi)*8 + ks) * 64 + lane) * 8);
#pragma unroll
            for (int g = 0; g < 4; ++g)
                acc2[mi][g] = __builtin_amdgcn_mfma_f32_16x16x32_f16(afr, bfr[g], acc2[mi][g], 0, 0, 0);
        }
    }

    // out = h + silu(acc2 + nb2) -> float4 stores
#pragma unroll
    for (int g = 0; g < 4; ++g) {
        int orow = blockIdx.x * 64 + g*16 + l15;
        if (orow < N_NODES) {
#pragma unroll
            for (int mi = 0; mi < 4; ++mi) {
                int hc0 = (w*4 + mi) * 16 + q * 4;
                f32x4 b2v = *(const f32x4*)(nb2 + hc0);
                f32x4 hv  = *(const f32x4*)(h + (size_t)orow * 256 + hc0);
                f32x4 ov;
                ov[0] = hv[0] + fast_silu(acc2[mi][g][0] + b2v[0]);
                ov[1] = hv[1] + fast_silu(acc2[mi][g][1] + b2v[1]);
                ov[2] = hv[2] + fast_silu(acc2[mi][g][2] + b2v[2]);
                ov[3] = hv[3] + fast_silu(acc2[mi][g][3] + b2v[3]);
                *(f32x4*)(out + (size_t)orow * 256 + hc0) = ov;
            }
        }
    }
}

// ---------------------------------------------------------------------------
extern "C" void kernel_launch(void* const* d_in, const int* in_sizes, int n_in,
                              void* d_out, int out_size, void* d_ws, size_t ws_size,
                              hipStream_t stream) {
    const float* h          = (const float*)d_in[0];
    const float* lattices   = (const float*)d_in[2];
    const int*   edge_index = (const int*)d_in[3];
    const int*   edge2graph = (const int*)d_in[4];
    const float* frac_diff  = (const float*)d_in[5];
    const float* ln_gamma   = (const float*)d_in[6];
    const float* ln_beta    = (const float*)d_in[7];
    const float* eW1        = (const float*)d_in[8];
    const float* eb1        = (const float*)d_in[9];
    const float* eW2        = (const float*)d_in[10];
    const float* eb2        = (const float*)d_in[11];
    const float* nW1        = (const float*)d_in[12];
    const float* nb1        = (const float*)d_in[13];
    const float* nW2        = (const float*)d_in[14];
    const float* nb2        = (const float*)d_in[15];
    float* out = (float*)d_out;
    char* base = (char*)d_ws;

    // workspace layout (byte offsets)
    float* aggsum   = (float*)(base + 0);              // 51,200,000 B
    int*   cnt      = (int*)  (base + 51200000);       // 200,704
    int*   off      = (int*)  (base + 51400704);       // 200,704
    int*   tmp      = (int*)  (base + 51601408);       // 200,704 (slots 50000+ reused as scan scratch)
    int*   sorted_e = (int*)  (base + 51802112);       // 2,000,000
    f16*   latW16   = (f16*)  (base + 53802112);       // 65,536
    f16*   Hh1      = (f16*)  (base + 53867648);       // 25,600,000
    f16*   Hh2      = (f16*)  (base + 79467648);
    f16*   Nh       = (f16*)  (base + 105067648);
    f16*   packs    = (f16*)  (base + 130667648);
    f16* Wfd  = packs;            // 98,304 halfs (K=384)
    f16* Whi  = Wfd  + 98304;
    f16* Whj  = Whi  + 65536;
    f16* We2  = Whj  + 65536;
    f16* Wn1h = We2  + 65536;
    f16* Wn1a = Wn1h + 65536;
    f16* Wn2  = Wn1a + 65536;     // ends at byte 131,650,688
    if (ws_size < (size_t)131650688) return;

    int* partials = tmp + 50000;  // 49 ints (unused tail of tmp)
    int* blkbase  = tmp + 50080;  // 49 ints

    // zero aggsum + cnt + off + tmp
    hipMemsetAsync(base, 0, (size_t)51802112, stream);

    // fused: 7 weight packs + latW + histogram
    prep_fused<<<2322, 256, 0, stream>>>(
        eW1, eW2, nW1, nW2, Wfd, Whi, Whj, We2, Wn1h, Wn1a, Wn2,
        lattices, eb1, latW16, edge_index, cnt);

    scan_part<<<49, 1024, 0, stream>>>(cnt, off, partials);
    scan_tops<<<1, 64, 0, stream>>>(partials, blkbase);

    // fused: CSR position-scatter + LayerNorm/3-GEMM (independent work)
    pos_ln_kernel<<<POS_BLOCKS + LN_BLOCKS, 256, 0, stream>>>(
        edge_index, off, blkbase, tmp, sorted_e,
        h, ln_gamma, ln_beta, Whi, Whj, Wn1h, Hh1, Hh2, Nh);

    edge_kernel<<<(E_EDGES + 63) / 64, 512, 0, stream>>>(
        sorted_e, edge_index, edge2graph, frac_diff, Hh1, Hh2, latW16, Wfd, We2, eb2, aggsum);

    node_post_kernel<<<(N_NODES + 63) / 64, 256, 0, stream>>>(
        aggsum, cnt, Nh, Wn1a, Wn2, nb1, nb2, h, out);
}

// Round 12
// 532.229 us; speedup vs baseline: 1.1523x; 1.0848x over previous
//
#include <hip/hip_runtime.h>
#include <hip/hip_bf16.h>
#include <math.h>

// Problem constants
#define N_NODES 50000
#define E_EDGES 500000
#define G_GRAPHS 128
#define N_PAD 50176   // 196*256 = 49*1024, padded node count for scan
#define POS_BLOCKS 977    // ceil(E/512)
#define LN_BLOCKS 391     // ceil(N/128)
// H = 256, NF = 64, EDGE_IN = 905 (rows: hi 0..255 | hj 256..511 | lat 512..520 | fd 521..904)

typedef _Float16 f16;
typedef _Float16 half8 __attribute__((ext_vector_type(8)));
typedef _Float16 half4 __attribute__((ext_vector_type(4)));
typedef float f32x4 __attribute__((ext_vector_type(4)));

// silu via v_rcp: avoids the precise-divide expansion (~9 instrs) of 1.0f/x
__device__ __forceinline__ float fast_silu(float x) {
    return x * __builtin_amdgcn_rcpf(1.0f + __expf(-x));
}

// ---------------------------------------------------------------------------
// Pack helper (device): [K x 256] row-major fp32 -> MFMA fragment-linear f16.
// chunk (nb, kstep): lane holds W[k=kstep*32+(lane>>4)*8+j][n=nb*16+(lane&15)].
// Serves BOTH as B-fragment (k,n) and as A-fragment (n,k) of W^T for the
// operand-swapped GEMMs.
// ---------------------------------------------------------------------------
__device__ __forceinline__ void pack_dev(const float* __restrict__ src,
                                         f16* __restrict__ dst, int Ksteps, int ltid) {
    int lane = ltid & 63;
    int chunk = ltid >> 6;
    int kstep = chunk % Ksteps;
    int nb = chunk / Ksteps;
    if (nb >= 16) return;
    int n = nb * 16 + (lane & 15);
    int k0 = kstep * 32 + (lane >> 4) * 8;
    f16* d = dst + (size_t)ltid * 8;
#pragma unroll
    for (int j = 0; j < 8; ++j)
        d[j] = (f16)src[(size_t)(k0 + j) * 256 + n];
}

// ---------------------------------------------------------------------------
// Fused prep: 7 weight packs + latW + edge histogram + aggsum zeroing in ONE
// launch. Block ranges: [0,48) Wfd | [48,80) Whi | [80,112) Whj | [112,144)
// We2 | [144,176) Wn1h | [176,208) Wn1a | [208,240) Wn2 | [240,368) latW |
// [368,2322) hist | [2322,2834) aggsum-zero (51.2 MB, overlapped with packs;
// safe because aggsum is first consumed by the later edge_kernel launch).
// ---------------------------------------------------------------------------
__global__ __launch_bounds__(256) void prep_fused(
    const float* __restrict__ eW1, const float* __restrict__ eW2,
    const float* __restrict__ nW1, const float* __restrict__ nW2,
    f16* __restrict__ Wfd, f16* __restrict__ Whi, f16* __restrict__ Whj,
    f16* __restrict__ We2, f16* __restrict__ Wn1h, f16* __restrict__ Wn1a,
    f16* __restrict__ Wn2,
    const float* __restrict__ lat, const float* __restrict__ eb1,
    f16* __restrict__ latW16,
    const int* __restrict__ ei, int* __restrict__ cnt,
    float* __restrict__ aggsum)
{
    int b = blockIdx.x, t = threadIdx.x;
    if (b < 48)        { pack_dev(eW1 + 521 * 256, Wfd,  12, b * 256 + t); }
    else if (b < 80)   { pack_dev(eW1,             Whi,  8, (b - 48) * 256 + t); }
    else if (b < 112)  { pack_dev(eW1 + 256 * 256, Whj,  8, (b - 80) * 256 + t); }
    else if (b < 144)  { pack_dev(eW2,             We2,  8, (b - 112) * 256 + t); }
    else if (b < 176)  { pack_dev(nW1,             Wn1h, 8, (b - 144) * 256 + t); }
    else if (b < 208)  { pack_dev(nW1 + 256 * 256, Wn1a, 8, (b - 176) * 256 + t); }
    else if (b < 240)  { pack_dev(nW2,             Wn2,  8, (b - 208) * 256 + t); }
    else if (b < 368) {
        int g = b - 240, n = t;
        float l[9];
#pragma unroll
        for (int i = 0; i < 9; ++i) l[i] = lat[g * 9 + i];
        float acc = eb1[n];
#pragma unroll
        for (int i = 0; i < 3; ++i)
#pragma unroll
            for (int j = 0; j < 3; ++j) {
                float ip = l[i*3+0]*l[j*3+0] + l[i*3+1]*l[j*3+1] + l[i*3+2]*l[j*3+2];
                acc += ip * eW1[(size_t)(512 + i*3 + j) * 256 + n];
            }
        latW16[g * 256 + n] = (f16)acc;
    } else if (b < 2322) {
        int e = (b - 368) * 256 + t;
        if (e < E_EDGES) atomicAdd(cnt + ei[e], 1);
    } else {
        // aggsum zero: 12,800,000 floats = 3,200,000 float4; 512 blocks.
        const f32x4 z = {0.f, 0.f, 0.f, 0.f};
        int idx = (b - 2322) * 256 + t;
        f32x4* p = (f32x4*)aggsum;
        for (int i = idx; i < 3200000; i += 512 * 256)
            p[i] = z;
    }
}

// ---------------------------------------------------------------------------
// Parallel CSR scan: per-block exclusive scan + block totals, then a single
// wave scans the 49 totals. pos adds base[s>>10].
// ---------------------------------------------------------------------------
__global__ __launch_bounds__(1024) void scan_part(const int* __restrict__ cnt,
                                                  int* __restrict__ off,
                                                  int* __restrict__ partials) {
    __shared__ int wsum[16], wpre[16];
    int t = threadIdx.x, lane = t & 63, w = t >> 6;
    int c = blockIdx.x * 1024 + t;
    int v = cnt[c];
    int x = v;
#pragma unroll
    for (int d = 1; d < 64; d <<= 1) { int nn = __shfl_up(x, d); if (lane >= d) x += nn; }
    if (lane == 63) wsum[w] = x;
    __syncthreads();
    if (t < 16) {
        int s = wsum[t];
        int y = s;
#pragma unroll
        for (int d = 1; d < 16; d <<= 1) { int nn = __shfl_up(y, d, 16); if (t >= d) y += nn; }
        wpre[t] = y - s;
        if (t == 15) partials[blockIdx.x] = y;
    }
    __syncthreads();
    off[c] = wpre[w] + x - v;   // block-local exclusive
}

__global__ void scan_tops(const int* __restrict__ partials, int* __restrict__ base) {
    int t = threadIdx.x;   // 64 threads, 49 used
    int v = (t < 49) ? partials[t] : 0;
    int x = v;
#pragma unroll
    for (int d = 1; d < 64; d <<= 1) { int nn = __shfl_up(x, d); if (t >= d) x += nn; }
    if (t < 49) base[t] = x - v;   // exclusive
}

// ---------------------------------------------------------------------------
// FUSED pos + ln_gemm, M=128 node tile, 512 threads. The ln part previously
// read 3x128 KB packed weights per 64-node block; doubling the tile halves
// per-node weight L2 traffic (the R11 edge-kernel lever applied here).
// LDS 67.6 KB -> 2 blocks/CU = 16 waves/CU, same wave count as before.
// Blocks [0, POS_BLOCKS): scatter (512 edges/block). Rest: ln tiles.
// ---------------------------------------------------------------------------
__global__ __launch_bounds__(512) void pos_ln_kernel(
    const int* __restrict__ ei, const int* __restrict__ off,
    const int* __restrict__ base, int* __restrict__ tmp,
    int* __restrict__ sorted_e,
    const float* __restrict__ h, const float* __restrict__ gamma, const float* __restrict__ beta,
    const f16* __restrict__ Whi, const f16* __restrict__ Whj, const f16* __restrict__ Wn1,
    f16* __restrict__ Hh1, f16* __restrict__ Hh2, f16* __restrict__ Nh)
{
    __shared__ f16 Aln[128 * 264];   // 67.6 KB
    int tid = threadIdx.x;

    if (blockIdx.x < POS_BLOCKS) {
        int e = blockIdx.x * 512 + tid;
        if (e < E_EDGES) {
            int s = ei[e];
            int p = off[s] + base[s >> 10] + atomicAdd(tmp + s, 1);
            sorted_e[p] = e;
        }
        return;
    }
    int lb = blockIdx.x - POS_BLOCKS;

    // ---- LayerNorm load phase: 16-lanes-per-row; 32 rows per round x 4.
    int l15g = tid & 15;          // col-group lane
    int rq   = tid >> 4;          // 0..31: row slot within a round

    float4 gv[4], bv[4];
#pragma unroll
    for (int i = 0; i < 4; ++i) {
        gv[i] = ((const float4*)gamma)[l15g + 16*i];
        bv[i] = ((const float4*)beta )[l15g + 16*i];
    }

#pragma unroll
    for (int r4 = 0; r4 < 4; ++r4) {
        int rl = r4 * 32 + rq;                 // local row 0..127
        int row = lb * 128 + rl;
        int rowc = min(row, N_NODES - 1);
        const float4* hp4 = (const float4*)(h + (size_t)rowc * 256);
        float4 xv[4];
        float s = 0.f, ss = 0.f;
#pragma unroll
        for (int i = 0; i < 4; ++i) {
            float4 x = hp4[l15g + 16*i];
            xv[i] = x;
            s  += x.x + x.y + x.z + x.w;
            ss += x.x*x.x + x.y*x.y + x.z*x.z + x.w*x.w;
        }
#pragma unroll
        for (int m = 1; m < 16; m <<= 1) {
            s  += __shfl_xor(s,  m);
            ss += __shfl_xor(ss, m);
        }
        float mean = s * (1.f / 256.f);
        float var  = ss * (1.f / 256.f) - mean * mean;
        float rstd = rsqrtf(var + 1e-5f);
#pragma unroll
        for (int i = 0; i < 4; ++i) {
            half4 o;
            o[0] = (f16)((xv[i].x - mean) * rstd * gv[i].x + bv[i].x);
            o[1] = (f16)((xv[i].y - mean) * rstd * gv[i].y + bv[i].y);
            o[2] = (f16)((xv[i].z - mean) * rstd * gv[i].z + bv[i].z);
            o[3] = (f16)((xv[i].w - mean) * rstd * gv[i].w + bv[i].w);
            *(half4*)(Aln + rl * 264 + (l15g + 16*i) * 4) = o;
        }
    }
    __syncthreads();

    int lane = tid & 63, w = tid >> 6;   // w 0..7
    int l15 = lane & 15, q = lane >> 4;
    const f16* Ws[3] = {Whi, Whj, Wn1};
    f16* Os[3] = {Hh1, Hh2, Nh};
    const f32x4 z4 = {0.f, 0.f, 0.f, 0.f};

    for (int widx = 0; widx < 3; ++widx) {
        f32x4 acc[2][8];   // [mi Hcol-block][g node-group]
#pragma unroll
        for (int a = 0; a < 2; ++a)
#pragma unroll
            for (int b = 0; b < 8; ++b) acc[a][b] = z4;
        const f16* W = Ws[widx];
        for (int ks = 0; ks < 8; ++ks) {
            half8 bfr[8];
#pragma unroll
            for (int g = 0; g < 8; ++g)
                bfr[g] = *(const half8*)(Aln + (g*16 + l15) * 264 + ks*32 + q*8);
#pragma unroll
            for (int mi = 0; mi < 2; ++mi) {
                half8 afr = *(const half8*)(W + ((size_t)((w*2 + mi)*8 + ks) * 64 + lane) * 8);
#pragma unroll
                for (int g = 0; g < 8; ++g)
                    acc[mi][g] = __builtin_amdgcn_mfma_f32_16x16x32_f16(afr, bfr[g], acc[mi][g], 0, 0, 0);
            }
        }
        f16* O = Os[widx];
#pragma unroll
        for (int g = 0; g < 8; ++g) {
            int orow = lb * 128 + g*16 + l15;
            if (orow < N_NODES) {
#pragma unroll
                for (int mi = 0; mi < 2; ++mi) {
                    int hc0 = (w*2 + mi) * 16 + q * 4;
                    half4 hv;
                    hv[0] = (f16)acc[mi][g][0]; hv[1] = (f16)acc[mi][g][1];
                    hv[2] = (f16)acc[mi][g][2]; hv[3] = (f16)acc[mi][g][3];
                    *(half4*)(O + (size_t)orow * 256 + hc0) = hv;
                }
            }
        }
    }
}

// ---------------------------------------------------------------------------
// Edge kernel v16 (unchanged from R11): M=64 tile, 512 threads, LDS 70.7 KB
// -> 2 blocks/CU = 16 waves/CU; weight L2 traffic 5 KB/edge.
// ---------------------------------------------------------------------------
__global__ __launch_bounds__(512, 4) void edge_kernel(
    const int* __restrict__ sorted_e,
    const int* __restrict__ edge_index, const int* __restrict__ edge2graph,
    const float* __restrict__ frac_diff,
    const f16* __restrict__ Hh1, const f16* __restrict__ Hh2, const f16* __restrict__ latW16,
    const f16* __restrict__ Wfd, const f16* __restrict__ We2, const float* __restrict__ eb2,
    float* __restrict__ aggsum)
{
    __shared__ f16 bufA[64 * 264];   // 33.8 KB: R tile -> e1 tile, row-major [edge][264]
    __shared__ f16 bufB[17408];      // 34.8 KB: frag window (24.6) / e2 tile [256][68]
    __shared__ float frac_s[64][4];
    __shared__ int src_s[64], dst_s[64], g_s[64], srcr[64];
    int tid = threadIdx.x;
    int e0 = blockIdx.x * 64;

    if (tid < 64) {
        int slot = e0 + tid;
        int e = (slot < E_EDGES) ? sorted_e[slot] : -1;
        int ec = e < 0 ? 0 : e;
        int sv = edge_index[ec];
        src_s[tid] = sv;
        dst_s[tid] = edge_index[E_EDGES + ec];
        g_s[tid]   = edge2graph[ec];
        srcr[tid]  = (e < 0) ? -1 : sv;
        frac_s[tid][0] = frac_diff[(size_t)ec * 3 + 0];
        frac_s[tid][1] = frac_diff[(size_t)ec * 3 + 1];
        frac_s[tid][2] = frac_diff[(size_t)ec * 3 + 2];
    }
    __syncthreads();   // B1: indices + frac ready

    // Stage one pass: 768 units (row 64, z 3, q2 4), <=2 per thread.
    auto stage_pass = [&](int p) {
#pragma unroll
        for (int uu = 0; uu < 2; ++uu) {
            int u = tid + uu * 512;
            if (u < 768) {
                int row = u & 63;
                int zz = u >> 6;           // 0..11 = z*4 + q2
                int z = zz >> 2, q2 = zz & 3;
                int kg = p * 3 + z;
                int d = kg >> 1, fb = kg & 1;
                float x = frac_s[row][d];
                float c1 = __builtin_amdgcn_cosf(x);
                float s1 = __builtin_amdgcn_sinf(x);
                float t0 = x * (float)(fb * 32 + q2 * 8);
                float rev = t0 - floorf(t0);
                float s = __builtin_amdgcn_sinf(rev);
                float c = __builtin_amdgcn_cosf(rev);
                f16 avs[8], avc[8];
#pragma unroll
                for (int j = 0; j < 8; ++j) {
                    avs[j] = (f16)s; avc[j] = (f16)c;
                    float ns = s * c1 + c * s1;
                    float nc = c * c1 - s * s1;
                    s = ns; c = nc;
                }
                int mb = row >> 4;                  // edge-group 0..3
                int lslot = (row & 15) + 16 * q2;
                *(half8*)(bufB + (((z    ) * 4 + mb) * 64 + lslot) * 8) = *(half8*)avs;
                *(half8*)(bufB + (((z + 3) * 4 + mb) * 64 + lslot) * 8) = *(half8*)avc;
            }
        }
    };

    // ---- R-fill: thread owns row m = tid>>3 (0..63); chunks (tid&7) + 8*i.
    {
        int m = tid >> 3, c0 = tid & 7;
        const f16* pa = Hh1    + (size_t)src_s[m] * 256 + c0 * 8;
        const f16* pb = Hh2    + (size_t)dst_s[m] * 256 + c0 * 8;
        const f16* pc = latW16 + (size_t)g_s[m]   * 256 + c0 * 8;
        f16* pd = bufA + m * 264 + c0 * 8;
#pragma unroll
        for (int i = 0; i < 4; ++i) {
            half8 a = *(const half8*)(pa + i * 64);
            half8 b = *(const half8*)(pb + i * 64);
            half8 c = *(const half8*)(pc + i * 64);
            *(half8*)(pd + i * 64) = a + b + c;
        }
    }
    stage_pass(0);
    __syncthreads();   // B2: R tile + pass-0 frags ready

    int lane = tid & 63, w = tid >> 6;   // w 0..7
    int l15 = lane & 15, q = lane >> 4;

    // ---- swapped GEMM1: e1^T[Hcol][edge] = Wfd^T @ fd^T + R^T.
    f32x4 acc[2][4];
#pragma unroll
    for (int mi = 0; mi < 2; ++mi)
#pragma unroll
        for (int g = 0; g < 4; ++g) {
            int edge = g * 16 + l15;
            int hc0 = (w*2 + mi) * 16 + q * 4;
            half4 rv = *(const half4*)(bufA + edge * 264 + hc0);
            f32x4 a;
            a[0] = (float)rv[0]; a[1] = (float)rv[1];
            a[2] = (float)rv[2]; a[3] = (float)rv[3];
            acc[mi][g] = a;
        }

#pragma unroll
    for (int p = 0; p < 2; ++p) {
        if (p == 1) {
            __syncthreads();   // B2b: pass-0 frag reads done
            stage_pass(1);
            __syncthreads();   // B2c: pass-1 frags ready
        }
#pragma unroll
        for (int z = 0; z < 3; ++z) {
            int kg = p * 3 + z;
            half8 aS[2], aC[2];
#pragma unroll
            for (int mi = 0; mi < 2; ++mi) {
                int mblk = w * 2 + mi;
                aS[mi] = *(const half8*)(Wfd + ((size_t)(mblk*12 + kg)     * 64 + lane) * 8);
                aC[mi] = *(const half8*)(Wfd + ((size_t)(mblk*12 + kg + 6) * 64 + lane) * 8);
            }
#pragma unroll
            for (int g = 0; g < 4; ++g) {
                half8 bS = *(const half8*)(bufB + (((z    ) * 4 + g) * 64 + lane) * 8);
                half8 bC = *(const half8*)(bufB + (((z + 3) * 4 + g) * 64 + lane) * 8);
#pragma unroll
                for (int mi = 0; mi < 2; ++mi) {
                    acc[mi][g] = __builtin_amdgcn_mfma_f32_16x16x32_f16(aS[mi], bS, acc[mi][g], 0, 0, 0);
                    acc[mi][g] = __builtin_amdgcn_mfma_f32_16x16x32_f16(aC[mi], bC, acc[mi][g], 0, 0, 0);
                }
            }
        }
    }

    // ---- epilogue 1: silu -> e1 row-major [edge][264] (owner-exclusive)
#pragma unroll
    for (int mi = 0; mi < 2; ++mi)
#pragma unroll
        for (int g = 0; g < 4; ++g) {
            int edge = g * 16 + l15;
            int hc0 = (w*2 + mi) * 16 + q * 4;
            half4 tv;
            tv[0] = (f16)fast_silu(acc[mi][g][0]);
            tv[1] = (f16)fast_silu(acc[mi][g][1]);
            tv[2] = (f16)fast_silu(acc[mi][g][2]);
            tv[3] = (f16)fast_silu(acc[mi][g][3]);
            *(half4*)(bufA + edge * 264 + hc0) = tv;
        }
    __syncthreads();   // B3: e1 tile ready (also: all pass-1 frag reads done)

    // ---- swapped GEMM2: e2^T = We2^T @ e1^T
    f32x4 acc2[2][4];
    const f32x4 z4 = {0.f, 0.f, 0.f, 0.f};
#pragma unroll
    for (int a = 0; a < 2; ++a)
#pragma unroll
        for (int b = 0; b < 4; ++b) acc2[a][b] = z4;
#pragma unroll
    for (int ks = 0; ks < 8; ++ks) {
        half8 bfr[4];
#pragma unroll
        for (int g = 0; g < 4; ++g)
            bfr[g] = *(const half8*)(bufA + (g*16 + l15) * 264 + ks*32 + q*8);
#pragma unroll
        for (int mi = 0; mi < 2; ++mi) {
            half8 afr = *(const half8*)(We2 + ((size_t)((w*2 + mi)*8 + ks) * 64 + lane) * 8);
#pragma unroll
            for (int g = 0; g < 4; ++g)
                acc2[mi][g] = __builtin_amdgcn_mfma_f32_16x16x32_f16(afr, bfr[g], acc2[mi][g], 0, 0, 0);
        }
    }

    // ---- epilogue 2: silu(+eb2) -> e2 tile [Hcol][edge pad68] f16 in bufB
    {
        float msk[4];
#pragma unroll
        for (int g = 0; g < 4; ++g)
            msk[g] = (srcr[g*16 + l15] >= 0) ? 1.f : 0.f;
#pragma unroll
        for (int mi = 0; mi < 2; ++mi) {
            int hc0 = (w*2 + mi) * 16 + q * 4;
            float4 e4 = *(const float4*)(eb2 + hc0);
#pragma unroll
            for (int g = 0; g < 4; ++g) {
                int edge = g * 16 + l15;
                bufB[(hc0 + 0) * 68 + edge] = (f16)(fast_silu(acc2[mi][g][0] + e4.x) * msk[g]);
                bufB[(hc0 + 1) * 68 + edge] = (f16)(fast_silu(acc2[mi][g][1] + e4.y) * msk[g]);
                bufB[(hc0 + 2) * 68 + edge] = (f16)(fast_silu(acc2[mi][g][2] + e4.z) * msk[g]);
                bufB[(hc0 + 3) * 68 + edge] = (f16)(fast_silu(acc2[mi][g][3] + e4.w) * msk[g]);
            }
        }
    }
    __syncthreads();   // B4: e2 tile ready

    // ---- segmented reduction: 2 threads per Hcol, 32 rows each (b64 reads).
    {
        int t = tid & 255, hf = tid >> 8;
        int r0 = hf * 32;
        float run = 0.f;
        int cur = srcr[r0];
#pragma unroll
        for (int m4 = 0; m4 < 8; ++m4) {
            half4 vv = *(const half4*)(bufB + t * 68 + r0 + m4 * 4);
#pragma unroll
            for (int jj = 0; jj < 4; ++jj) {
                int mm = r0 + m4 * 4 + jj;
                int s = srcr[mm];
                float v = (float)vv[jj];
                if (s != cur) {
                    if (cur >= 0) atomicAdd(aggsum + (size_t)cur * 256 + t, run);
                    cur = s; run = v;
                } else run += v;
            }
        }
        if (cur >= 0) atomicAdd(aggsum + (size_t)cur * 256 + t, run);
    }
}

// ---------------------------------------------------------------------------
// Node post, M=128 tile, 512 threads: agg = aggsum/max(cnt,1);
// t = silu(Nh + agg@Wn1a + nb1); out = h + silu(t@Wn2 + nb2).
// Per-node weight L2 traffic halved vs the 64-node tile; LDS 67.6 KB ->
// 2 blocks/CU = 16 waves/CU (same wave count as before).
// ---------------------------------------------------------------------------
__global__ __launch_bounds__(512) void node_post_kernel(
    const float* __restrict__ aggsum, const int* __restrict__ cnt,
    const f16* __restrict__ Nh, const f16* __restrict__ Wn1a, const f16* __restrict__ Wn2,
    const float* __restrict__ nb1, const float* __restrict__ nb2,
    const float* __restrict__ h, float* __restrict__ out)
{
    __shared__ f16 T[128 * 264];   // 67.6 KB
    int tid = threadIdx.x;
    int lane = tid & 63, w = tid >> 6;   // w 0..7
    {
#pragma unroll
        for (int i = 0; i < 16; ++i) {
            int rl = w + 8 * i;                 // local row 0..127, wave-uniform
            int row = blockIdx.x * 128 + rl;
            int rowc = min(row, N_NODES - 1);
            float inv = 1.f / fmaxf((float)cnt[rowc], 1.f);
            float4 x = ((const float4*)(aggsum + (size_t)rowc * 256))[lane];
            half4 av;
            av[0] = (f16)(x.x * inv);
            av[1] = (f16)(x.y * inv);
            av[2] = (f16)(x.z * inv);
            av[3] = (f16)(x.w * inv);
            *(half4*)(T + rl * 264 + lane * 4) = av;
        }
    }
    __syncthreads();

    int l15 = lane & 15, q = lane >> 4;
    const f32x4 z4 = {0.f, 0.f, 0.f, 0.f};

    // GEMM1 swapped: acc[mi][g], A = Wn1a frag, B = T rows (agg)
    f32x4 acc[2][8];
#pragma unroll
    for (int a = 0; a < 2; ++a)
#pragma unroll
        for (int b = 0; b < 8; ++b) acc[a][b] = z4;
    for (int ks = 0; ks < 8; ++ks) {
        half8 bfr[8];
#pragma unroll
        for (int g = 0; g < 8; ++g)
            bfr[g] = *(const half8*)(T + (g*16 + l15) * 264 + ks*32 + q*8);
#pragma unroll
        for (int mi = 0; mi < 2; ++mi) {
            half8 afr = *(const half8*)(Wn1a + ((size_t)((w*2 + mi)*8 + ks) * 64 + lane) * 8);
#pragma unroll
            for (int g = 0; g < 8; ++g)
                acc[mi][g] = __builtin_amdgcn_mfma_f32_16x16x32_f16(afr, bfr[g], acc[mi][g], 0, 0, 0);
        }
    }
    __syncthreads();   // all T reads done

    // t = silu(acc + Nh + nb1) -> T'[node][hc0..3] half4 writes
#pragma unroll
    for (int mi = 0; mi < 2; ++mi) {
        int hc0 = (w*2 + mi) * 16 + q * 4;
        f32x4 b1v = *(const f32x4*)(nb1 + hc0);
#pragma unroll
        for (int g = 0; g < 8; ++g) {
            int nodeg = blockIdx.x * 128 + g*16 + l15;
            int orc = min(nodeg, N_NODES - 1);
            half4 nh4 = *(const half4*)(Nh + (size_t)orc * 256 + hc0);
            half4 tv;
            tv[0] = (f16)fast_silu(acc[mi][g][0] + (float)nh4[0] + b1v[0]);
            tv[1] = (f16)fast_silu(acc[mi][g][1] + (float)nh4[1] + b1v[1]);
            tv[2] = (f16)fast_silu(acc[mi][g][2] + (float)nh4[2] + b1v[2]);
            tv[3] = (f16)fast_silu(acc[mi][g][3] + (float)nh4[3] + b1v[3]);
            *(half4*)(T + (g*16 + l15) * 264 + hc0) = tv;
        }
    }
    __syncthreads();

    // GEMM2 swapped: A = Wn2 frag, B = T' rows
    f32x4 acc2[2][8];
#pragma unroll
    for (int a = 0; a < 2; ++a)
#pragma unroll
        for (int b = 0; b < 8; ++b) acc2[a][b] = z4;
    for (int ks = 0; ks < 8; ++ks) {
        half8 bfr[8];
#pragma unroll
        for (int g = 0; g < 8; ++g)
            bfr[g] = *(const half8*)(T + (g*16 + l15) * 264 + ks*32 + q*8);
#pragma unroll
        for (int mi = 0; mi < 2; ++mi) {
            half8 afr = *(const half8*)(Wn2 + ((size_t)((w*2 + mi)*8 + ks) * 64 + lane) * 8);
#pragma unroll
            for (int g = 0; g < 8; ++g)
                acc2[mi][g] = __builtin_amdgcn_mfma_f32_16x16x32_f16(afr, bfr[g], acc2[mi][g], 0, 0, 0);
        }
    }

    // out = h + silu(acc2 + nb2) -> float4 stores
#pragma unroll
    for (int g = 0; g < 8; ++g) {
        int orow = blockIdx.x * 128 + g*16 + l15;
        if (orow < N_NODES) {
#pragma unroll
            for (int mi = 0; mi < 2; ++mi) {
                int hc0 = (w*2 + mi) * 16 + q * 4;
                f32x4 b2v = *(const f32x4*)(nb2 + hc0);
                f32x4 hv  = *(const f32x4*)(h + (size_t)orow * 256 + hc0);
                f32x4 ov;
                ov[0] = hv[0] + fast_silu(acc2[mi][g][0] + b2v[0]);
                ov[1] = hv[1] + fast_silu(acc2[mi][g][1] + b2v[1]);
                ov[2] = hv[2] + fast_silu(acc2[mi][g][2] + b2v[2]);
                ov[3] = hv[3] + fast_silu(acc2[mi][g][3] + b2v[3]);
                *(f32x4*)(out + (size_t)orow * 256 + hc0) = ov;
            }
        }
    }
}

// ---------------------------------------------------------------------------
extern "C" void kernel_launch(void* const* d_in, const int* in_sizes, int n_in,
                              void* d_out, int out_size, void* d_ws, size_t ws_size,
                              hipStream_t stream) {
    const float* h          = (const float*)d_in[0];
    const float* lattices   = (const float*)d_in[2];
    const int*   edge_index = (const int*)d_in[3];
    const int*   edge2graph = (const int*)d_in[4];
    const float* frac_diff  = (const float*)d_in[5];
    const float* ln_gamma   = (const float*)d_in[6];
    const float* ln_beta    = (const float*)d_in[7];
    const float* eW1        = (const float*)d_in[8];
    const float* eb1        = (const float*)d_in[9];
    const float* eW2        = (const float*)d_in[10];
    const float* eb2        = (const float*)d_in[11];
    const float* nW1        = (const float*)d_in[12];
    const float* nb1        = (const float*)d_in[13];
    const float* nW2        = (const float*)d_in[14];
    const float* nb2        = (const float*)d_in[15];
    float* out = (float*)d_out;
    char* base = (char*)d_ws;

    // workspace layout (byte offsets)
    float* aggsum   = (float*)(base + 0);              // 51,200,000 B
    int*   cnt      = (int*)  (base + 51200000);       // 200,704
    int*   off      = (int*)  (base + 51400704);       // 200,704
    int*   tmp      = (int*)  (base + 51601408);       // 200,704 (slots 50000+ reused as scan scratch)
    int*   sorted_e = (int*)  (base + 51802112);       // 2,000,000
    f16*   latW16   = (f16*)  (base + 53802112);       // 65,536
    f16*   Hh1      = (f16*)  (base + 53867648);       // 25,600,000
    f16*   Hh2      = (f16*)  (base + 79467648);
    f16*   Nh       = (f16*)  (base + 105067648);
    f16*   packs    = (f16*)  (base + 130667648);
    f16* Wfd  = packs;            // 98,304 halfs (K=384)
    f16* Whi  = Wfd  + 98304;
    f16* Whj  = Whi  + 65536;
    f16* We2  = Whj  + 65536;
    f16* Wn1h = We2  + 65536;
    f16* Wn1a = Wn1h + 65536;
    f16* Wn2  = Wn1a + 65536;     // ends at byte 131,650,688
    if (ws_size < (size_t)131650688) return;

    int* partials = tmp + 50000;  // 49 ints (unused tail of tmp)
    int* blkbase  = tmp + 50080;  // 49 ints

    // zero cnt + off + tmp only (602,112 B); aggsum zeroed inside prep_fused
    hipMemsetAsync(base + 51200000, 0, (size_t)602112, stream);

    // fused: 7 weight packs + latW + histogram + aggsum zeroing
    prep_fused<<<2834, 256, 0, stream>>>(
        eW1, eW2, nW1, nW2, Wfd, Whi, Whj, We2, Wn1h, Wn1a, Wn2,
        lattices, eb1, latW16, edge_index, cnt, aggsum);

    scan_part<<<49, 1024, 0, stream>>>(cnt, off, partials);
    scan_tops<<<1, 64, 0, stream>>>(partials, blkbase);

    // fused: CSR position-scatter + LayerNorm/3-GEMM (independent work)
    pos_ln_kernel<<<POS_BLOCKS + LN_BLOCKS, 512, 0, stream>>>(
        edge_index, off, blkbase, tmp, sorted_e,
        h, ln_gamma, ln_beta, Whi, Whj, Wn1h, Hh1, Hh2, Nh);

    edge_kernel<<<(E_EDGES + 63) / 64, 512, 0, stream>>>(
        sorted_e, edge_index, edge2graph, frac_diff, Hh1, Hh2, latW16, Wfd, We2, eb2, aggsum);

    node_post_kernel<<<(N_NODES + 127) / 128, 512, 0, stream>>>(
        aggsum, cnt, Nh, Wn1a, Wn2, nb1, nb2, h, out);
}